// Round 1
// baseline (1200.406 us; speedup 1.0000x reference)
//
#include <hip/hip_runtime.h>
#include <hip/hip_bf16.h>

#define EPS 1e-5f

// ---------------- CSR build ----------------
__global__ void k_hist(const int* __restrict__ dst, int* __restrict__ cnt, int E) {
  for (int e = blockIdx.x * blockDim.x + threadIdx.x; e < E; e += gridDim.x * blockDim.x)
    atomicAdd(&cnt[dst[e]], 1);
}

__global__ void k_dis(const int* __restrict__ cnt, float* __restrict__ dis, int N) {
  int i = blockIdx.x * blockDim.x + threadIdx.x;
  if (i < N) dis[i] = rsqrtf((float)cnt[i] + 1.0f);
}

__global__ void k_scan_block(const int* __restrict__ in, int* __restrict__ out,
                             int* __restrict__ bsum, int N) {
  __shared__ int tmp[256];
  int lid = threadIdx.x;
  int i = blockIdx.x * 256 + lid;
  int v = (i < N) ? in[i] : 0;
  tmp[lid] = v;
  __syncthreads();
  for (int off = 1; off < 256; off <<= 1) {
    int t = (lid >= off) ? tmp[lid - off] : 0;
    __syncthreads();
    tmp[lid] += t;
    __syncthreads();
  }
  if (i < N) out[i] = tmp[lid] - v;            // exclusive within block
  if (lid == 255) bsum[blockIdx.x] = tmp[255];
}

__global__ void k_scan_bsum(const int* __restrict__ bsum, int* __restrict__ bexc, int nb) {
  __shared__ int tmp[512];
  int lid = threadIdx.x;
  int v = (lid < nb) ? bsum[lid] : 0;
  tmp[lid] = v;
  __syncthreads();
  for (int off = 1; off < 512; off <<= 1) {
    int t = (lid >= off) ? tmp[lid - off] : 0;
    __syncthreads();
    tmp[lid] += t;
    __syncthreads();
  }
  if (lid < nb) bexc[lid] = tmp[lid] - v;      // exclusive
}

__global__ void k_add_back(int* __restrict__ offs, const int* __restrict__ bexc,
                           int* __restrict__ cur, int N, int E) {
  int i = blockIdx.x * 256 + threadIdx.x;
  if (i < N) {
    int v = offs[i] + bexc[blockIdx.x];
    offs[i] = v;
    cur[i] = v;
  }
  if (i == 0) offs[N] = E;
}

__global__ void k_fill(const int* __restrict__ src, const int* __restrict__ dst,
                       const float* __restrict__ dis, int* __restrict__ cur,
                       int* __restrict__ csr_src, float* __restrict__ csr_w, int E) {
  for (int e = blockIdx.x * blockDim.x + threadIdx.x; e < E; e += gridDim.x * blockDim.x) {
    int s = src[e], d = dst[e];
    int p = atomicAdd(&cur[d], 1);
    csr_src[p] = s;
    csr_w[p] = dis[s] * dis[d];
  }
}

// ---------------- layer 1 (aggregate 13(->16) features, then K=13 GEMM) ----------------
__global__ void k_padx(const float* __restrict__ x, float* __restrict__ x16, int N) {
  int i = blockIdx.x * blockDim.x + threadIdx.x;
  if (i >= N * 16) return;
  int n = i >> 4, f = i & 15;
  x16[i] = (f < 13) ? x[n * 13 + f] : 0.0f;
}

__global__ __launch_bounds__(64) void k_agg16(
    const float* __restrict__ h, const int* __restrict__ csr_src,
    const float* __restrict__ csr_w, const int* __restrict__ offs,
    const float* __restrict__ dis, float* __restrict__ out, int N) {
  int node = (blockIdx.x << 2) + (threadIdx.x >> 4);
  int f = threadIdx.x & 15;
  if (node >= N) return;
  float dn = dis[node];
  float acc = h[(size_t)node * 16 + f] * dn * dn;
  int beg = offs[node], end = offs[node + 1];
  for (int i = beg; i < end; ++i) {
    int s = csr_src[i];
    acc = fmaf(h[(size_t)s * 16 + f], csr_w[i], acc);
  }
  out[(size_t)node * 16 + f] = acc;
}

__global__ __launch_bounds__(256) void k_gemm1(
    const float* __restrict__ ax, const float* __restrict__ W1,
    const float* __restrict__ bb, const float* __restrict__ gg,
    const float* __restrict__ be, const float* __restrict__ mm,
    const float* __restrict__ vv, float* __restrict__ out, int N) {
  int idx = blockIdx.x * 256 + threadIdx.x;
  int node = idx >> 7, c = idx & 127;
  if (node >= N) return;
  float s = gg[c] * rsqrtf(vv[c] + EPS);
  float tt = be[c] + (bb[c] - mm[c]) * s;
  float acc = 0.f;
#pragma unroll
  for (int k = 0; k < 13; ++k)
    acc = fmaf(ax[(size_t)node * 16 + k], W1[k * 128 + c], acc);
  out[(size_t)node * 128 + c] = fmaxf(fmaf(acc, s, tt), 0.f);
}

// ---------------- 128-feature aggregation ----------------
__global__ __launch_bounds__(256) void k_agg128(
    const float* __restrict__ h, const int* __restrict__ csr_src,
    const float* __restrict__ csr_w, const int* __restrict__ offs,
    const float* __restrict__ dis, float* __restrict__ out, int N) {
  int node = (blockIdx.x << 1) + (threadIdx.x >> 7);
  int f = threadIdx.x & 127;
  if (node >= N) return;
  float dn = dis[node];
  float acc = h[(size_t)node * 128 + f] * dn * dn;
  int beg = offs[node], end = offs[node + 1];
  for (int i = beg; i < end; ++i) {
    int s = csr_src[i];
    float w = csr_w[i];
    acc = fmaf(h[(size_t)s * 128 + f], w, acc);
  }
  out[(size_t)node * 128 + f] = acc;
}

// ---------------- H x H fp32 GEMM (64x64 tile, 4x4 per thread) + BN/ReLU epilogue ----------------
__global__ __launch_bounds__(256) void k_gemm_hh(
    const float* __restrict__ A, const float* __restrict__ W,
    const float* __restrict__ bb, const float* __restrict__ gg,
    const float* __restrict__ be, const float* __restrict__ mm,
    const float* __restrict__ vv, float* __restrict__ out, int N) {
  __shared__ float a_lds[64 * 128];   // A tile, k-group XOR-swizzled
  __shared__ float w_lds[128 * 64];   // W column tile
  const int tid = threadIdx.x;
  const int bc = blockIdx.x & 1;
  const int br = blockIdx.x >> 1;
  const int row0 = br * 64, col0 = bc * 64;

  for (int i = tid; i < 2048; i += 256) {       // 64 rows x 32 float4
    int r = i >> 5;
    int s = i & 31;
    int ss = s ^ ((r >> 2) & 3);
    float4 v = make_float4(0.f, 0.f, 0.f, 0.f);
    int row = row0 + r;
    if (row < N) v = *(const float4*)&A[(size_t)row * 128 + (s << 2)];
    *(float4*)&a_lds[r * 128 + (ss << 2)] = v;
  }
  for (int i = tid; i < 2048; i += 256) {       // 128 rows x 16 float4
    int k = i >> 4;
    int c4 = (i & 15) << 2;
    *(float4*)&w_lds[k * 64 + c4] = *(const float4*)&W[k * 128 + col0 + c4];
  }
  __syncthreads();

  const int tx = tid & 15, ty = tid >> 4;
  float acc[4][4] = {};
#pragma unroll 4
  for (int kq = 0; kq < 32; ++kq) {
    const int k = kq << 2;
    const int ss = kq ^ (ty & 3);
    float4 a0 = *(const float4*)&a_lds[(ty * 4 + 0) * 128 + (ss << 2)];
    float4 a1 = *(const float4*)&a_lds[(ty * 4 + 1) * 128 + (ss << 2)];
    float4 a2 = *(const float4*)&a_lds[(ty * 4 + 2) * 128 + (ss << 2)];
    float4 a3 = *(const float4*)&a_lds[(ty * 4 + 3) * 128 + (ss << 2)];
    float4 b0 = *(const float4*)&w_lds[(k + 0) * 64 + (tx << 2)];
    float4 b1 = *(const float4*)&w_lds[(k + 1) * 64 + (tx << 2)];
    float4 b2 = *(const float4*)&w_lds[(k + 2) * 64 + (tx << 2)];
    float4 b3 = *(const float4*)&w_lds[(k + 3) * 64 + (tx << 2)];

    acc[0][0] += a0.x*b0.x + a0.y*b1.x + a0.z*b2.x + a0.w*b3.x;
    acc[0][1] += a0.x*b0.y + a0.y*b1.y + a0.z*b2.y + a0.w*b3.y;
    acc[0][2] += a0.x*b0.z + a0.y*b1.z + a0.z*b2.z + a0.w*b3.z;
    acc[0][3] += a0.x*b0.w + a0.y*b1.w + a0.z*b2.w + a0.w*b3.w;
    acc[1][0] += a1.x*b0.x + a1.y*b1.x + a1.z*b2.x + a1.w*b3.x;
    acc[1][1] += a1.x*b0.y + a1.y*b1.y + a1.z*b2.y + a1.w*b3.y;
    acc[1][2] += a1.x*b0.z + a1.y*b1.z + a1.z*b2.z + a1.w*b3.z;
    acc[1][3] += a1.x*b0.w + a1.y*b1.w + a1.z*b2.w + a1.w*b3.w;
    acc[2][0] += a2.x*b0.x + a2.y*b1.x + a2.z*b2.x + a2.w*b3.x;
    acc[2][1] += a2.x*b0.y + a2.y*b1.y + a2.z*b2.y + a2.w*b3.y;
    acc[2][2] += a2.x*b0.z + a2.y*b1.z + a2.z*b2.z + a2.w*b3.z;
    acc[2][3] += a2.x*b0.w + a2.y*b1.w + a2.z*b2.w + a2.w*b3.w;
    acc[3][0] += a3.x*b0.x + a3.y*b1.x + a3.z*b2.x + a3.w*b3.x;
    acc[3][1] += a3.x*b0.y + a3.y*b1.y + a3.z*b2.y + a3.w*b3.y;
    acc[3][2] += a3.x*b0.z + a3.y*b1.z + a3.z*b2.z + a3.w*b3.z;
    acc[3][3] += a3.x*b0.w + a3.y*b1.w + a3.z*b2.w + a3.w*b3.w;
  }

  float sj[4], tj[4];
#pragma unroll
  for (int j = 0; j < 4; ++j) {
    int c = col0 + (tx << 2) + j;
    float s = gg[c] * rsqrtf(vv[c] + EPS);
    sj[j] = s;
    tj[j] = be[c] + (bb[c] - mm[c]) * s;
  }
#pragma unroll
  for (int i = 0; i < 4; ++i) {
    int row = row0 + ty * 4 + i;
    if (row < N) {
      float4 o;
      o.x = fmaxf(fmaf(acc[i][0], sj[0], tj[0]), 0.f);
      o.y = fmaxf(fmaf(acc[i][1], sj[1], tj[1]), 0.f);
      o.z = fmaxf(fmaf(acc[i][2], sj[2], tj[2]), 0.f);
      o.w = fmaxf(fmaf(acc[i][3], sj[3], tj[3]), 0.f);
      *(float4*)&out[(size_t)row * 128 + col0 + (tx << 2)] = o;
    }
  }
}

// ---------------- pooling + classifier ----------------
__global__ void k_hist_batch(const int* __restrict__ batch, int* __restrict__ cnt, int N) {
  int i = blockIdx.x * blockDim.x + threadIdx.x;
  if (i < N) atomicAdd(&cnt[batch[i]], 1);
}

__global__ __launch_bounds__(128) void k_pool(
    const float* __restrict__ h, const int* __restrict__ batch,
    float* __restrict__ pooled, int N) {
  int f = threadIdx.x;
  int n0 = blockIdx.x * 128;
  int nEnd = min(n0 + 128, N);
  float acc = 0.f;
  int cur = -1;
  for (int nn = n0; nn < nEnd; ++nn) {
    int g = batch[nn];
    if (g != cur) {
      if (cur >= 0) atomicAdd(&pooled[cur * 128 + f], acc);
      cur = g;
      acc = 0.f;
    }
    acc += h[(size_t)nn * 128 + f];
  }
  if (cur >= 0) atomicAdd(&pooled[cur * 128 + f], acc);
}

__global__ __launch_bounds__(64) void k_cls(
    const float* __restrict__ pooled, const int* __restrict__ cnt,
    const float* __restrict__ Wc1, const float* __restrict__ bc1,
    const float* __restrict__ Wc2, const float* __restrict__ bc2,
    float* __restrict__ out, int G) {
  __shared__ float pm[128];
  __shared__ float hid[64];
  int g = blockIdx.x, t = threadIdx.x;
  float invc = 1.f / fmaxf((float)cnt[g], 1.f);
  pm[t]      = pooled[g * 128 + t] * invc;
  pm[t + 64] = pooled[g * 128 + 64 + t] * invc;
  __syncthreads();
  float a = bc1[t];
#pragma unroll 8
  for (int k = 0; k < 128; ++k) a = fmaf(pm[k], Wc1[k * 64 + t], a);
  hid[t] = fmaxf(a, 0.f);
  __syncthreads();
  if (t < 10) {
    float a2 = bc2[t];
#pragma unroll
    for (int j = 0; j < 64; ++j) a2 = fmaf(hid[j], Wc2[j * 10 + t], a2);
    out[g * 10 + t] = a2;
  }
}

extern "C" void kernel_launch(void* const* d_in, const int* in_sizes, int n_in,
                              void* d_out, int out_size, void* d_ws, size_t ws_size,
                              hipStream_t stream) {
  const float* x   = (const float*)d_in[0];
  const int*   ei  = (const int*)d_in[1];
  const int* batch = (const int*)d_in[2];
  const float* W1 = (const float*)d_in[3];
  const float* b1 = (const float*)d_in[4];
  const float* g1 = (const float*)d_in[5];
  const float* be1 = (const float*)d_in[6];
  const float* m1 = (const float*)d_in[7];
  const float* v1 = (const float*)d_in[8];
  const float* W2 = (const float*)d_in[9];
  const float* b2 = (const float*)d_in[10];
  const float* g2 = (const float*)d_in[11];
  const float* be2 = (const float*)d_in[12];
  const float* m2 = (const float*)d_in[13];
  const float* v2 = (const float*)d_in[14];
  const float* W3 = (const float*)d_in[15];
  const float* b3 = (const float*)d_in[16];
  const float* g3 = (const float*)d_in[17];
  const float* be3 = (const float*)d_in[18];
  const float* m3 = (const float*)d_in[19];
  const float* v3 = (const float*)d_in[20];
  const float* Wc1 = (const float*)d_in[21];
  const float* bc1 = (const float*)d_in[22];
  const float* Wc2 = (const float*)d_in[23];
  const float* bc2 = (const float*)d_in[24];

  const int N = in_sizes[0] / 13;
  const int E = in_sizes[1] / 2;
  const int G = out_size / 10;
  const int* src = ei;
  const int* dst = ei + E;

  char* ws = (char*)d_ws;
  size_t off = 0;
  auto alloc = [&](size_t bytes) {
    char* p = ws + off;
    off = (off + bytes + 255) & ~(size_t)255;
    return p;
  };
  int*   deg    = (int*)  alloc((size_t)N * 4);
  float* dis    = (float*)alloc((size_t)N * 4);
  int*   offs   = (int*)  alloc((size_t)(N + 1) * 4);
  int*   curp   = (int*)  alloc((size_t)N * 4);
  const int nb  = (N + 255) / 256;
  int*   bsum   = (int*)  alloc((size_t)nb * 4);
  int*   bexc   = (int*)  alloc((size_t)nb * 4);
  int*   csr_s  = (int*)  alloc((size_t)E * 4);
  float* csr_w  = (float*)alloc((size_t)E * 4);
  float* bufA   = (float*)alloc((size_t)N * 128 * 4);
  float* bufB   = (float*)alloc((size_t)N * 128 * 4);
  float* pooled = (float*)alloc((size_t)G * 128 * 4);
  int*   cntg   = (int*)  alloc((size_t)G * 4);
  float* x16 = bufA;  // [N,16] lives in bufA space (dead before bufA is rewritten)
  float* ax  = bufB;  // [N,16] lives in bufB space

  hipMemsetAsync(deg, 0, (size_t)N * 4, stream);
  hipMemsetAsync(pooled, 0, (size_t)G * 128 * 4, stream);
  hipMemsetAsync(cntg, 0, (size_t)G * 4, stream);

  k_hist<<<2048, 256, 0, stream>>>(dst, deg, E);
  k_dis<<<(N + 255) / 256, 256, 0, stream>>>(deg, dis, N);
  k_scan_block<<<nb, 256, 0, stream>>>(deg, offs, bsum, N);
  k_scan_bsum<<<1, 512, 0, stream>>>(bsum, bexc, nb);
  k_add_back<<<nb, 256, 0, stream>>>(offs, bexc, curp, N, E);
  k_fill<<<2048, 256, 0, stream>>>(src, dst, dis, curp, csr_s, csr_w, E);

  k_padx<<<(N * 16 + 255) / 256, 256, 0, stream>>>(x, x16, N);
  k_agg16<<<(N + 3) / 4, 64, 0, stream>>>(x16, csr_s, csr_w, offs, dis, ax, N);
  k_gemm1<<<(N * 128 + 255) / 256, 256, 0, stream>>>(ax, W1, b1, g1, be1, m1, v1, bufA, N);

  const int gemmGrid = ((N + 63) / 64) * 2;
  k_agg128<<<(N + 1) / 2, 256, 0, stream>>>(bufA, csr_s, csr_w, offs, dis, bufB, N);
  k_gemm_hh<<<gemmGrid, 256, 0, stream>>>(bufB, W2, b2, g2, be2, m2, v2, bufA, N);
  k_agg128<<<(N + 1) / 2, 256, 0, stream>>>(bufA, csr_s, csr_w, offs, dis, bufB, N);
  k_gemm_hh<<<gemmGrid, 256, 0, stream>>>(bufB, W3, b3, g3, be3, m3, v3, bufA, N);

  k_hist_batch<<<(N + 255) / 256, 256, 0, stream>>>(batch, cntg, N);
  k_pool<<<(N + 127) / 128, 128, 0, stream>>>(bufA, batch, pooled, N);
  k_cls<<<G, 64, 0, stream>>>(pooled, cntg, Wc1, bc1, Wc2, bc2, (float*)d_out, G);
}

// Round 3
// 846.541 us; speedup vs baseline: 1.4180x; 1.4180x over previous
//
#include <hip/hip_runtime.h>
#include <hip/hip_bf16.h>

#define EPS 1e-5f

// ---------------- CSR build ----------------
__global__ void k_hist(const int* __restrict__ dst, int* __restrict__ cnt, int E) {
  for (int e = blockIdx.x * blockDim.x + threadIdx.x; e < E; e += gridDim.x * blockDim.x)
    atomicAdd(&cnt[dst[e]], 1);
}

__global__ void k_dis(const int* __restrict__ cnt, float* __restrict__ dis, int N) {
  int i = blockIdx.x * blockDim.x + threadIdx.x;
  if (i < N) dis[i] = rsqrtf((float)cnt[i] + 1.0f);
}

__global__ void k_scan_block(const int* __restrict__ in, int* __restrict__ out,
                             int* __restrict__ bsum, int N) {
  __shared__ int tmp[256];
  int lid = threadIdx.x;
  int i = blockIdx.x * 256 + lid;
  int v = (i < N) ? in[i] : 0;
  tmp[lid] = v;
  __syncthreads();
  for (int off = 1; off < 256; off <<= 1) {
    int t = (lid >= off) ? tmp[lid - off] : 0;
    __syncthreads();
    tmp[lid] += t;
    __syncthreads();
  }
  if (i < N) out[i] = tmp[lid] - v;            // exclusive within block
  if (lid == 255) bsum[blockIdx.x] = tmp[255];
}

__global__ void k_scan_bsum(const int* __restrict__ bsum, int* __restrict__ bexc, int nb) {
  __shared__ int tmp[512];
  int lid = threadIdx.x;
  int v = (lid < nb) ? bsum[lid] : 0;
  tmp[lid] = v;
  __syncthreads();
  for (int off = 1; off < 512; off <<= 1) {
    int t = (lid >= off) ? tmp[lid - off] : 0;
    __syncthreads();
    tmp[lid] += t;
    __syncthreads();
  }
  if (lid < nb) bexc[lid] = tmp[lid] - v;      // exclusive
}

__global__ void k_add_back(int* __restrict__ offs, const int* __restrict__ bexc,
                           int* __restrict__ cur, int N, int E) {
  int i = blockIdx.x * 256 + threadIdx.x;
  if (i < N) {
    int v = offs[i] + bexc[blockIdx.x];
    offs[i] = v;
    cur[i] = v;
  }
  if (i == 0) offs[N] = E;
}

// packed CSR entry: .x = src node, .y = float bits of edge weight
__global__ void k_fill(const int* __restrict__ src, const int* __restrict__ dst,
                       const float* __restrict__ dis, int* __restrict__ cur,
                       int2* __restrict__ csr, int E) {
  for (int e = blockIdx.x * blockDim.x + threadIdx.x; e < E; e += gridDim.x * blockDim.x) {
    int s = src[e], d = dst[e];
    int p = atomicAdd(&cur[d], 1);
    float w = dis[s] * dis[d];
    csr[p] = make_int2(s, __float_as_int(w));
  }
}

// ---------------- layer 1 (aggregate 13(->16) features, then K=13 GEMM) ----------------
__global__ void k_padx(const float* __restrict__ x, float* __restrict__ x16, int N) {
  int i = blockIdx.x * blockDim.x + threadIdx.x;
  if (i >= N * 16) return;
  int n = i >> 4, f = i & 15;
  x16[i] = (f < 13) ? x[n * 13 + f] : 0.0f;
}

__global__ __launch_bounds__(64) void k_agg16(
    const float* __restrict__ h, const int2* __restrict__ csr,
    const int* __restrict__ offs, const float* __restrict__ dis,
    float* __restrict__ out, int N) {
  int node = (blockIdx.x << 2) + (threadIdx.x >> 4);
  int f = threadIdx.x & 15;
  if (node >= N) return;
  float dn = dis[node];
  float a0 = h[(size_t)node * 16 + f] * dn * dn;
  float a1 = 0.f, a2 = 0.f, a3 = 0.f;
  int beg = offs[node], end = offs[node + 1];
  int i = beg;
  for (; i + 4 <= end; i += 4) {
    int2 e0 = csr[i + 0], e1 = csr[i + 1], e2 = csr[i + 2], e3 = csr[i + 3];
    float v0 = h[(size_t)e0.x * 16 + f];
    float v1 = h[(size_t)e1.x * 16 + f];
    float v2 = h[(size_t)e2.x * 16 + f];
    float v3 = h[(size_t)e3.x * 16 + f];
    a0 = fmaf(v0, __int_as_float(e0.y), a0);
    a1 = fmaf(v1, __int_as_float(e1.y), a1);
    a2 = fmaf(v2, __int_as_float(e2.y), a2);
    a3 = fmaf(v3, __int_as_float(e3.y), a3);
  }
  for (; i < end; ++i) {
    int2 e = csr[i];
    a0 = fmaf(h[(size_t)e.x * 16 + f], __int_as_float(e.y), a0);
  }
  out[(size_t)node * 16 + f] = (a0 + a1) + (a2 + a3);
}

__global__ __launch_bounds__(256) void k_gemm1(
    const float* __restrict__ ax, const float* __restrict__ W1,
    const float* __restrict__ bb, const float* __restrict__ gg,
    const float* __restrict__ be, const float* __restrict__ mm,
    const float* __restrict__ vv, float* __restrict__ out, int N) {
  int idx = blockIdx.x * 256 + threadIdx.x;
  int node = idx >> 7, c = idx & 127;
  if (node >= N) return;
  float s = gg[c] * rsqrtf(vv[c] + EPS);
  float tt = be[c] + (bb[c] - mm[c]) * s;
  float acc = 0.f;
#pragma unroll
  for (int k = 0; k < 13; ++k)
    acc = fmaf(ax[(size_t)node * 16 + k], W1[k * 128 + c], acc);
  out[(size_t)node * 128 + c] = fmaxf(fmaf(acc, s, tt), 0.f);
}

// ---------------- 128-feature aggregation: 1 wave per node, float2/lane, 8-deep ILP ----
__global__ __launch_bounds__(256) void k_agg128(
    const float* __restrict__ h, const int2* __restrict__ csr,
    const int* __restrict__ offs, const float* __restrict__ dis,
    float* __restrict__ out, int N) {
  int node = (blockIdx.x << 2) + (threadIdx.x >> 6);
  if (node >= N) return;
  int lane = threadIdx.x & 63;
  const float2* __restrict__ h2 = (const float2*)h;
  float dn = dis[node];
  int beg = offs[node], end = offs[node + 1];
  float2 self = h2[(size_t)node * 64 + lane];
  float s2 = dn * dn;
  float2 a0 = make_float2(self.x * s2, self.y * s2);
  float2 a1 = make_float2(0.f, 0.f), a2 = a1, a3 = a1;
  float2 a4 = a1, a5 = a1, a6 = a1, a7 = a1;
  int i = beg;
  for (; i + 8 <= end; i += 8) {
    int2 e0 = csr[i + 0], e1 = csr[i + 1], e2 = csr[i + 2], e3 = csr[i + 3];
    int2 e4 = csr[i + 4], e5 = csr[i + 5], e6 = csr[i + 6], e7 = csr[i + 7];
    float2 v0 = h2[(size_t)e0.x * 64 + lane];
    float2 v1 = h2[(size_t)e1.x * 64 + lane];
    float2 v2 = h2[(size_t)e2.x * 64 + lane];
    float2 v3 = h2[(size_t)e3.x * 64 + lane];
    float2 v4 = h2[(size_t)e4.x * 64 + lane];
    float2 v5 = h2[(size_t)e5.x * 64 + lane];
    float2 v6 = h2[(size_t)e6.x * 64 + lane];
    float2 v7 = h2[(size_t)e7.x * 64 + lane];
    float w0 = __int_as_float(e0.y), w1 = __int_as_float(e1.y);
    float w2 = __int_as_float(e2.y), w3 = __int_as_float(e3.y);
    float w4 = __int_as_float(e4.y), w5 = __int_as_float(e5.y);
    float w6 = __int_as_float(e6.y), w7 = __int_as_float(e7.y);
    a0.x = fmaf(v0.x, w0, a0.x); a0.y = fmaf(v0.y, w0, a0.y);
    a1.x = fmaf(v1.x, w1, a1.x); a1.y = fmaf(v1.y, w1, a1.y);
    a2.x = fmaf(v2.x, w2, a2.x); a2.y = fmaf(v2.y, w2, a2.y);
    a3.x = fmaf(v3.x, w3, a3.x); a3.y = fmaf(v3.y, w3, a3.y);
    a4.x = fmaf(v4.x, w4, a4.x); a4.y = fmaf(v4.y, w4, a4.y);
    a5.x = fmaf(v5.x, w5, a5.x); a5.y = fmaf(v5.y, w5, a5.y);
    a6.x = fmaf(v6.x, w6, a6.x); a6.y = fmaf(v6.y, w6, a6.y);
    a7.x = fmaf(v7.x, w7, a7.x); a7.y = fmaf(v7.y, w7, a7.y);
  }
  for (; i < end; ++i) {
    int2 e = csr[i];
    float2 v = h2[(size_t)e.x * 64 + lane];
    float w = __int_as_float(e.y);
    a0.x = fmaf(v.x, w, a0.x); a0.y = fmaf(v.y, w, a0.y);
  }
  float2 r;
  r.x = ((a0.x + a1.x) + (a2.x + a3.x)) + ((a4.x + a5.x) + (a6.x + a7.x));
  r.y = ((a0.y + a1.y) + (a2.y + a3.y)) + ((a4.y + a5.y) + (a6.y + a7.y));
  ((float2*)out)[(size_t)node * 64 + lane] = r;
}

// ---------------- H x H fp32 GEMM (64x64 tile, 4x4 per thread) + BN/ReLU epilogue ----------------
__global__ __launch_bounds__(256) void k_gemm_hh(
    const float* __restrict__ A, const float* __restrict__ W,
    const float* __restrict__ bb, const float* __restrict__ gg,
    const float* __restrict__ be, const float* __restrict__ mm,
    const float* __restrict__ vv, float* __restrict__ out, int N) {
  __shared__ float a_lds[64 * 128];   // A tile, k-group XOR-swizzled
  __shared__ float w_lds[128 * 64];   // W column tile
  const int tid = threadIdx.x;
  const int bc = blockIdx.x & 1;
  const int br = blockIdx.x >> 1;
  const int row0 = br * 64, col0 = bc * 64;

  for (int i = tid; i < 2048; i += 256) {       // 64 rows x 32 float4
    int r = i >> 5;
    int s = i & 31;
    int ss = s ^ ((r >> 2) & 3);
    float4 v = make_float4(0.f, 0.f, 0.f, 0.f);
    int row = row0 + r;
    if (row < N) v = *(const float4*)&A[(size_t)row * 128 + (s << 2)];
    *(float4*)&a_lds[r * 128 + (ss << 2)] = v;
  }
  for (int i = tid; i < 2048; i += 256) {       // 128 rows x 16 float4
    int k = i >> 4;
    int c4 = (i & 15) << 2;
    *(float4*)&w_lds[k * 64 + c4] = *(const float4*)&W[k * 128 + col0 + c4];
  }
  __syncthreads();

  const int tx = tid & 15, ty = tid >> 4;
  float acc[4][4] = {};
#pragma unroll 4
  for (int kq = 0; kq < 32; ++kq) {
    const int k = kq << 2;
    const int ss = kq ^ (ty & 3);
    float4 a0 = *(const float4*)&a_lds[(ty * 4 + 0) * 128 + (ss << 2)];
    float4 a1 = *(const float4*)&a_lds[(ty * 4 + 1) * 128 + (ss << 2)];
    float4 a2 = *(const float4*)&a_lds[(ty * 4 + 2) * 128 + (ss << 2)];
    float4 a3 = *(const float4*)&a_lds[(ty * 4 + 3) * 128 + (ss << 2)];
    float4 b0 = *(const float4*)&w_lds[(k + 0) * 64 + (tx << 2)];
    float4 b1 = *(const float4*)&w_lds[(k + 1) * 64 + (tx << 2)];
    float4 b2 = *(const float4*)&w_lds[(k + 2) * 64 + (tx << 2)];
    float4 b3 = *(const float4*)&w_lds[(k + 3) * 64 + (tx << 2)];

    acc[0][0] += a0.x*b0.x + a0.y*b1.x + a0.z*b2.x + a0.w*b3.x;
    acc[0][1] += a0.x*b0.y + a0.y*b1.y + a0.z*b2.y + a0.w*b3.y;
    acc[0][2] += a0.x*b0.z + a0.y*b1.z + a0.z*b2.z + a0.w*b3.z;
    acc[0][3] += a0.x*b0.w + a0.y*b1.w + a0.z*b2.w + a0.w*b3.w;
    acc[1][0] += a1.x*b0.x + a1.y*b1.x + a1.z*b2.x + a1.w*b3.x;
    acc[1][1] += a1.x*b0.y + a1.y*b1.y + a1.z*b2.y + a1.w*b3.y;
    acc[1][2] += a1.x*b0.z + a1.y*b1.z + a1.z*b2.z + a1.w*b3.z;
    acc[1][3] += a1.x*b0.w + a1.y*b1.w + a1.z*b2.w + a1.w*b3.w;
    acc[2][0] += a2.x*b0.x + a2.y*b1.x + a2.z*b2.x + a2.w*b3.x;
    acc[2][1] += a2.x*b0.y + a2.y*b1.y + a2.z*b2.y + a2.w*b3.y;
    acc[2][2] += a2.x*b0.z + a2.y*b1.z + a2.z*b2.z + a2.w*b3.z;
    acc[2][3] += a2.x*b0.w + a2.y*b1.w + a2.z*b2.w + a2.w*b3.w;
    acc[3][0] += a3.x*b0.x + a3.y*b1.x + a3.z*b2.x + a3.w*b3.x;
    acc[3][1] += a3.x*b0.y + a3.y*b1.y + a3.z*b2.y + a3.w*b3.y;
    acc[3][2] += a3.x*b0.z + a3.y*b1.z + a3.z*b2.z + a3.w*b3.z;
    acc[3][3] += a3.x*b0.w + a3.y*b1.w + a3.z*b2.w + a3.w*b3.w;
  }

  float sj[4], tj[4];
#pragma unroll
  for (int j = 0; j < 4; ++j) {
    int c = col0 + (tx << 2) + j;
    float s = gg[c] * rsqrtf(vv[c] + EPS);
    sj[j] = s;
    tj[j] = be[c] + (bb[c] - mm[c]) * s;
  }
#pragma unroll
  for (int i = 0; i < 4; ++i) {
    int row = row0 + ty * 4 + i;
    if (row < N) {
      float4 o;
      o.x = fmaxf(fmaf(acc[i][0], sj[0], tj[0]), 0.f);
      o.y = fmaxf(fmaf(acc[i][1], sj[1], tj[1]), 0.f);
      o.z = fmaxf(fmaf(acc[i][2], sj[2], tj[2]), 0.f);
      o.w = fmaxf(fmaf(acc[i][3], sj[3], tj[3]), 0.f);
      *(float4*)&out[(size_t)row * 128 + col0 + (tx << 2)] = o;
    }
  }
}

// ---------------- pooling + classifier ----------------
__global__ void k_hist_batch(const int* __restrict__ batch, int* __restrict__ cnt, int N) {
  int i = blockIdx.x * blockDim.x + threadIdx.x;
  if (i < N) atomicAdd(&cnt[batch[i]], 1);
}

__global__ __launch_bounds__(128) void k_pool(
    const float* __restrict__ h, const int* __restrict__ batch,
    float* __restrict__ pooled, int N) {
  int f = threadIdx.x;
  int n0 = blockIdx.x * 128;
  int nEnd = min(n0 + 128, N);
  float acc = 0.f;
  int cur = -1;
  for (int nn = n0; nn < nEnd; ++nn) {
    int g = batch[nn];
    if (g != cur) {
      if (cur >= 0) atomicAdd(&pooled[cur * 128 + f], acc);
      cur = g;
      acc = 0.f;
    }
    acc += h[(size_t)nn * 128 + f];
  }
  if (cur >= 0) atomicAdd(&pooled[cur * 128 + f], acc);
}

__global__ __launch_bounds__(64) void k_cls(
    const float* __restrict__ pooled, const int* __restrict__ cnt,
    const float* __restrict__ Wc1, const float* __restrict__ bc1,
    const float* __restrict__ Wc2, const float* __restrict__ bc2,
    float* __restrict__ out, int G) {
  __shared__ float pm[128];
  __shared__ float hid[64];
  int g = blockIdx.x, t = threadIdx.x;
  float invc = 1.f / fmaxf((float)cnt[g], 1.f);
  pm[t]      = pooled[g * 128 + t] * invc;
  pm[t + 64] = pooled[g * 128 + 64 + t] * invc;
  __syncthreads();
  float a = bc1[t];
#pragma unroll 8
  for (int k = 0; k < 128; ++k) a = fmaf(pm[k], Wc1[k * 64 + t], a);
  hid[t] = fmaxf(a, 0.f);
  __syncthreads();
  if (t < 10) {
    float a2 = bc2[t];
#pragma unroll
    for (int j = 0; j < 64; ++j) a2 = fmaf(hid[j], Wc2[j * 10 + t], a2);
    out[g * 10 + t] = a2;
  }
}

extern "C" void kernel_launch(void* const* d_in, const int* in_sizes, int n_in,
                              void* d_out, int out_size, void* d_ws, size_t ws_size,
                              hipStream_t stream) {
  const float* x   = (const float*)d_in[0];
  const int*   ei  = (const int*)d_in[1];
  const int* batch = (const int*)d_in[2];
  const float* W1 = (const float*)d_in[3];
  const float* b1 = (const float*)d_in[4];
  const float* g1 = (const float*)d_in[5];
  const float* be1 = (const float*)d_in[6];
  const float* m1 = (const float*)d_in[7];
  const float* v1 = (const float*)d_in[8];
  const float* W2 = (const float*)d_in[9];
  const float* b2 = (const float*)d_in[10];
  const float* g2 = (const float*)d_in[11];
  const float* be2 = (const float*)d_in[12];
  const float* m2 = (const float*)d_in[13];
  const float* v2 = (const float*)d_in[14];
  const float* W3 = (const float*)d_in[15];
  const float* b3 = (const float*)d_in[16];
  const float* g3 = (const float*)d_in[17];
  const float* be3 = (const float*)d_in[18];
  const float* m3 = (const float*)d_in[19];
  const float* v3 = (const float*)d_in[20];
  const float* Wc1 = (const float*)d_in[21];
  const float* bc1 = (const float*)d_in[22];
  const float* Wc2 = (const float*)d_in[23];
  const float* bc2 = (const float*)d_in[24];

  const int N = in_sizes[0] / 13;
  const int E = in_sizes[1] / 2;
  const int G = out_size / 10;
  const int* src = ei;
  const int* dst = ei + E;

  char* ws = (char*)d_ws;
  size_t off = 0;
  auto alloc = [&](size_t bytes) {
    char* p = ws + off;
    off = (off + bytes + 255) & ~(size_t)255;
    return p;
  };
  int*   deg    = (int*)  alloc((size_t)N * 4);
  float* dis    = (float*)alloc((size_t)N * 4);
  int*   offs   = (int*)  alloc((size_t)(N + 1) * 4);
  int*   curp   = (int*)  alloc((size_t)N * 4);
  const int nb  = (N + 255) / 256;
  int*   bsum   = (int*)  alloc((size_t)nb * 4);
  int*   bexc   = (int*)  alloc((size_t)nb * 4);
  int2*  csr    = (int2*) alloc((size_t)E * 8);
  float* bufA   = (float*)alloc((size_t)N * 128 * 4);
  float* bufB   = (float*)alloc((size_t)N * 128 * 4);
  float* pooled = (float*)alloc((size_t)G * 128 * 4);
  int*   cntg   = (int*)  alloc((size_t)G * 4);
  float* x16 = bufA;  // [N,16] lives in bufA space (dead before bufA is rewritten)
  float* ax  = bufB;  // [N,16] lives in bufB space

  hipMemsetAsync(deg, 0, (size_t)N * 4, stream);
  hipMemsetAsync(pooled, 0, (size_t)G * 128 * 4, stream);
  hipMemsetAsync(cntg, 0, (size_t)G * 4, stream);

  k_hist<<<2048, 256, 0, stream>>>(dst, deg, E);
  k_dis<<<(N + 255) / 256, 256, 0, stream>>>(deg, dis, N);
  k_scan_block<<<nb, 256, 0, stream>>>(deg, offs, bsum, N);
  k_scan_bsum<<<1, 512, 0, stream>>>(bsum, bexc, nb);
  k_add_back<<<nb, 256, 0, stream>>>(offs, bexc, curp, N, E);
  k_fill<<<2048, 256, 0, stream>>>(src, dst, dis, curp, csr, E);

  k_padx<<<(N * 16 + 255) / 256, 256, 0, stream>>>(x, x16, N);
  k_agg16<<<(N + 3) / 4, 64, 0, stream>>>(x16, csr, offs, dis, ax, N);
  k_gemm1<<<(N * 128 + 255) / 256, 256, 0, stream>>>(ax, W1, b1, g1, be1, m1, v1, bufA, N);

  const int gemmGrid = ((N + 63) / 64) * 2;
  k_agg128<<<(N + 3) / 4, 256, 0, stream>>>(bufA, csr, offs, dis, bufB, N);
  k_gemm_hh<<<gemmGrid, 256, 0, stream>>>(bufB, W2, b2, g2, be2, m2, v2, bufA, N);
  k_agg128<<<(N + 3) / 4, 256, 0, stream>>>(bufA, csr, offs, dis, bufB, N);
  k_gemm_hh<<<gemmGrid, 256, 0, stream>>>(bufB, W3, b3, g3, be3, m3, v3, bufA, N);

  k_hist_batch<<<(N + 255) / 256, 256, 0, stream>>>(batch, cntg, N);
  k_pool<<<(N + 127) / 128, 128, 0, stream>>>(bufA, batch, pooled, N);
  k_cls<<<G, 64, 0, stream>>>(pooled, cntg, Wc1, bc1, Wc2, bc2, (float*)d_out, G);
}

// Round 4
// 841.919 us; speedup vs baseline: 1.4258x; 1.0055x over previous
//
#include <hip/hip_runtime.h>
#include <hip/hip_bf16.h>

#define EPS 1e-5f

// ---------------- CSR build ----------------
__global__ void k_hist(const int* __restrict__ dst, int* __restrict__ cnt, int E) {
  for (int e = blockIdx.x * blockDim.x + threadIdx.x; e < E; e += gridDim.x * blockDim.x)
    atomicAdd(&cnt[dst[e]], 1);
}

__global__ void k_dis(const int* __restrict__ cnt, float* __restrict__ dis, int N) {
  int i = blockIdx.x * blockDim.x + threadIdx.x;
  if (i < N) dis[i] = rsqrtf((float)cnt[i] + 1.0f);
}

__global__ void k_scan_block(const int* __restrict__ in, int* __restrict__ out,
                             int* __restrict__ bsum, int N) {
  __shared__ int tmp[256];
  int lid = threadIdx.x;
  int i = blockIdx.x * 256 + lid;
  int v = (i < N) ? in[i] : 0;
  tmp[lid] = v;
  __syncthreads();
  for (int off = 1; off < 256; off <<= 1) {
    int t = (lid >= off) ? tmp[lid - off] : 0;
    __syncthreads();
    tmp[lid] += t;
    __syncthreads();
  }
  if (i < N) out[i] = tmp[lid] - v;            // exclusive within block
  if (lid == 255) bsum[blockIdx.x] = tmp[255];
}

__global__ void k_scan_bsum(const int* __restrict__ bsum, int* __restrict__ bexc, int nb) {
  __shared__ int tmp[512];
  int lid = threadIdx.x;
  int v = (lid < nb) ? bsum[lid] : 0;
  tmp[lid] = v;
  __syncthreads();
  for (int off = 1; off < 512; off <<= 1) {
    int t = (lid >= off) ? tmp[lid - off] : 0;
    __syncthreads();
    tmp[lid] += t;
    __syncthreads();
  }
  if (lid < nb) bexc[lid] = tmp[lid] - v;      // exclusive
}

__global__ void k_add_back(int* __restrict__ offs, const int* __restrict__ bexc,
                           int* __restrict__ cur, int N, int E) {
  int i = blockIdx.x * 256 + threadIdx.x;
  if (i < N) {
    int v = offs[i] + bexc[blockIdx.x];
    offs[i] = v;
    cur[i] = v;
  }
  if (i == 0) offs[N] = E;
}

// packed CSR entry: .x = src node, .y = float bits of edge weight
__global__ void k_fill(const int* __restrict__ src, const int* __restrict__ dst,
                       const float* __restrict__ dis, int* __restrict__ cur,
                       int2* __restrict__ csr, int E) {
  for (int e = blockIdx.x * blockDim.x + threadIdx.x; e < E; e += gridDim.x * blockDim.x) {
    int s = src[e], d = dst[e];
    int p = atomicAdd(&cur[d], 1);
    float w = dis[s] * dis[d];
    csr[p] = make_int2(s, __float_as_int(w));
  }
}

// ---------------- layer 1 (aggregate 13(->16) features, then K=13 GEMM) ----------------
__global__ void k_padx(const float* __restrict__ x, float* __restrict__ x16, int N) {
  int i = blockIdx.x * blockDim.x + threadIdx.x;
  if (i >= N * 16) return;
  int n = i >> 4, f = i & 15;
  x16[i] = (f < 13) ? x[n * 13 + f] : 0.0f;
}

__global__ __launch_bounds__(64) void k_agg16(
    const float* __restrict__ h, const int2* __restrict__ csr,
    const int* __restrict__ offs, const float* __restrict__ dis,
    float* __restrict__ out, int N) {
  int node = (blockIdx.x << 2) + (threadIdx.x >> 4);
  int f = threadIdx.x & 15;
  if (node >= N) return;
  float dn = dis[node];
  float a0 = h[(size_t)node * 16 + f] * dn * dn;
  float a1 = 0.f, a2 = 0.f, a3 = 0.f;
  int beg = offs[node], end = offs[node + 1];
  int i = beg;
  for (; i + 4 <= end; i += 4) {
    int2 e0 = csr[i + 0], e1 = csr[i + 1], e2 = csr[i + 2], e3 = csr[i + 3];
    float v0 = h[(size_t)e0.x * 16 + f];
    float v1 = h[(size_t)e1.x * 16 + f];
    float v2 = h[(size_t)e2.x * 16 + f];
    float v3 = h[(size_t)e3.x * 16 + f];
    a0 = fmaf(v0, __int_as_float(e0.y), a0);
    a1 = fmaf(v1, __int_as_float(e1.y), a1);
    a2 = fmaf(v2, __int_as_float(e2.y), a2);
    a3 = fmaf(v3, __int_as_float(e3.y), a3);
  }
  for (; i < end; ++i) {
    int2 e = csr[i];
    a0 = fmaf(h[(size_t)e.x * 16 + f], __int_as_float(e.y), a0);
  }
  out[(size_t)node * 16 + f] = (a0 + a1) + (a2 + a3);
}

__global__ __launch_bounds__(256) void k_gemm1(
    const float* __restrict__ ax, const float* __restrict__ W1,
    const float* __restrict__ bb, const float* __restrict__ gg,
    const float* __restrict__ be, const float* __restrict__ mm,
    const float* __restrict__ vv, float* __restrict__ out, int N) {
  int idx = blockIdx.x * 256 + threadIdx.x;
  int node = idx >> 7, c = idx & 127;
  if (node >= N) return;
  float s = gg[c] * rsqrtf(vv[c] + EPS);
  float tt = be[c] + (bb[c] - mm[c]) * s;
  float acc = 0.f;
#pragma unroll
  for (int k = 0; k < 13; ++k)
    acc = fmaf(ax[(size_t)node * 16 + k], W1[k * 128 + c], acc);
  out[(size_t)node * 128 + c] = fmaxf(fmaf(acc, s, tt), 0.f);
}

// ---- 128-feature aggregation: 1 wave/node, 2 edges/wave (float4 lanes), 8 pair-steps ----
__global__ __launch_bounds__(256) void k_agg128(
    const float* __restrict__ h, const int2* __restrict__ csr,
    const int* __restrict__ offs, const float* __restrict__ dis,
    float* __restrict__ out, int N) {
  int node = (blockIdx.x << 2) + (threadIdx.x >> 6);
  if (node >= N) return;
  const int lane = threadIdx.x & 63;
  const int half = lane >> 5;     // 0: edge A of pair, 1: edge B
  const int q = lane & 31;        // float4 slot within the 128-float row
  const float4* __restrict__ h4 = (const float4*)h;
  float dn = dis[node];
  int beg = offs[node], end = offs[node + 1];

  // self term (lanes 0-31 carry it; upper half weight 0)
  float4 sv = h4[(size_t)node * 32 + q];
  float ws = half ? 0.f : dn * dn;
  float4 a0 = make_float4(sv.x * ws, sv.y * ws, sv.z * ws, sv.w * ws);
  float4 z = make_float4(0.f, 0.f, 0.f, 0.f);
  float4 a1 = z, a2 = z, a3 = z, a4 = z, a5 = z, a6 = z, a7 = z;

  int i = beg;
  for (; i + 16 <= end; i += 16) {      // 8 pairs = 16 edges in flight
    int2 e0 = csr[i +  0 + half];
    int2 e1 = csr[i +  2 + half];
    int2 e2 = csr[i +  4 + half];
    int2 e3 = csr[i +  6 + half];
    int2 e4 = csr[i +  8 + half];
    int2 e5 = csr[i + 10 + half];
    int2 e6 = csr[i + 12 + half];
    int2 e7 = csr[i + 14 + half];
    float4 v0 = h4[(size_t)e0.x * 32 + q];
    float4 v1 = h4[(size_t)e1.x * 32 + q];
    float4 v2 = h4[(size_t)e2.x * 32 + q];
    float4 v3 = h4[(size_t)e3.x * 32 + q];
    float4 v4 = h4[(size_t)e4.x * 32 + q];
    float4 v5 = h4[(size_t)e5.x * 32 + q];
    float4 v6 = h4[(size_t)e6.x * 32 + q];
    float4 v7 = h4[(size_t)e7.x * 32 + q];
    float w0 = __int_as_float(e0.y), w1 = __int_as_float(e1.y);
    float w2 = __int_as_float(e2.y), w3 = __int_as_float(e3.y);
    float w4 = __int_as_float(e4.y), w5 = __int_as_float(e5.y);
    float w6 = __int_as_float(e6.y), w7 = __int_as_float(e7.y);
    a0.x = fmaf(v0.x, w0, a0.x); a0.y = fmaf(v0.y, w0, a0.y);
    a0.z = fmaf(v0.z, w0, a0.z); a0.w = fmaf(v0.w, w0, a0.w);
    a1.x = fmaf(v1.x, w1, a1.x); a1.y = fmaf(v1.y, w1, a1.y);
    a1.z = fmaf(v1.z, w1, a1.z); a1.w = fmaf(v1.w, w1, a1.w);
    a2.x = fmaf(v2.x, w2, a2.x); a2.y = fmaf(v2.y, w2, a2.y);
    a2.z = fmaf(v2.z, w2, a2.z); a2.w = fmaf(v2.w, w2, a2.w);
    a3.x = fmaf(v3.x, w3, a3.x); a3.y = fmaf(v3.y, w3, a3.y);
    a3.z = fmaf(v3.z, w3, a3.z); a3.w = fmaf(v3.w, w3, a3.w);
    a4.x = fmaf(v4.x, w4, a4.x); a4.y = fmaf(v4.y, w4, a4.y);
    a4.z = fmaf(v4.z, w4, a4.z); a4.w = fmaf(v4.w, w4, a4.w);
    a5.x = fmaf(v5.x, w5, a5.x); a5.y = fmaf(v5.y, w5, a5.y);
    a5.z = fmaf(v5.z, w5, a5.z); a5.w = fmaf(v5.w, w5, a5.w);
    a6.x = fmaf(v6.x, w6, a6.x); a6.y = fmaf(v6.y, w6, a6.y);
    a6.z = fmaf(v6.z, w6, a6.z); a6.w = fmaf(v6.w, w6, a6.w);
    a7.x = fmaf(v7.x, w7, a7.x); a7.y = fmaf(v7.y, w7, a7.y);
    a7.z = fmaf(v7.z, w7, a7.z); a7.w = fmaf(v7.w, w7, a7.w);
  }
  for (; i < end; i += 2) {             // remaining pairs (possibly ragged)
    int j = i + half;
    int jc = (j < end) ? j : (end - 1);
    int2 e = csr[jc];
    float w = (j < end) ? __int_as_float(e.y) : 0.f;
    float4 v = h4[(size_t)e.x * 32 + q];
    a0.x = fmaf(v.x, w, a0.x); a0.y = fmaf(v.y, w, a0.y);
    a0.z = fmaf(v.z, w, a0.z); a0.w = fmaf(v.w, w, a0.w);
  }

  float4 r;
  r.x = ((a0.x + a1.x) + (a2.x + a3.x)) + ((a4.x + a5.x) + (a6.x + a7.x));
  r.y = ((a0.y + a1.y) + (a2.y + a3.y)) + ((a4.y + a5.y) + (a6.y + a7.y));
  r.z = ((a0.z + a1.z) + (a2.z + a3.z)) + ((a4.z + a5.z) + (a6.z + a7.z));
  r.w = ((a0.w + a1.w) + (a2.w + a3.w)) + ((a4.w + a5.w) + (a6.w + a7.w));
  // combine edge-A half (lanes 0-31) with edge-B half (lanes 32-63)
  r.x += __shfl_xor(r.x, 32, 64);
  r.y += __shfl_xor(r.y, 32, 64);
  r.z += __shfl_xor(r.z, 32, 64);
  r.w += __shfl_xor(r.w, 32, 64);
  if (half == 0)
    ((float4*)out)[(size_t)node * 32 + q] = r;
}

// ---------------- H x H fp32 GEMM (64x64 tile, 4x4 per thread) + BN/ReLU epilogue ----------------
__global__ __launch_bounds__(256) void k_gemm_hh(
    const float* __restrict__ A, const float* __restrict__ W,
    const float* __restrict__ bb, const float* __restrict__ gg,
    const float* __restrict__ be, const float* __restrict__ mm,
    const float* __restrict__ vv, float* __restrict__ out, int N) {
  __shared__ float a_lds[64 * 128];   // A tile, k-group XOR-swizzled
  __shared__ float w_lds[128 * 64];   // W column tile
  const int tid = threadIdx.x;
  const int bc = blockIdx.x & 1;
  const int br = blockIdx.x >> 1;
  const int row0 = br * 64, col0 = bc * 64;

  for (int i = tid; i < 2048; i += 256) {       // 64 rows x 32 float4
    int r = i >> 5;
    int s = i & 31;
    int ss = s ^ ((r >> 2) & 3);
    float4 v = make_float4(0.f, 0.f, 0.f, 0.f);
    int row = row0 + r;
    if (row < N) v = *(const float4*)&A[(size_t)row * 128 + (s << 2)];
    *(float4*)&a_lds[r * 128 + (ss << 2)] = v;
  }
  for (int i = tid; i < 2048; i += 256) {       // 128 rows x 16 float4
    int k = i >> 4;
    int c4 = (i & 15) << 2;
    *(float4*)&w_lds[k * 64 + c4] = *(const float4*)&W[k * 128 + col0 + c4];
  }
  __syncthreads();

  const int tx = tid & 15, ty = tid >> 4;
  float acc[4][4] = {};
#pragma unroll 4
  for (int kq = 0; kq < 32; ++kq) {
    const int k = kq << 2;
    const int ss = kq ^ (ty & 3);
    float4 a0 = *(const float4*)&a_lds[(ty * 4 + 0) * 128 + (ss << 2)];
    float4 a1 = *(const float4*)&a_lds[(ty * 4 + 1) * 128 + (ss << 2)];
    float4 a2 = *(const float4*)&a_lds[(ty * 4 + 2) * 128 + (ss << 2)];
    float4 a3 = *(const float4*)&a_lds[(ty * 4 + 3) * 128 + (ss << 2)];
    float4 b0 = *(const float4*)&w_lds[(k + 0) * 64 + (tx << 2)];
    float4 b1 = *(const float4*)&w_lds[(k + 1) * 64 + (tx << 2)];
    float4 b2 = *(const float4*)&w_lds[(k + 2) * 64 + (tx << 2)];
    float4 b3 = *(const float4*)&w_lds[(k + 3) * 64 + (tx << 2)];

    acc[0][0] += a0.x*b0.x + a0.y*b1.x + a0.z*b2.x + a0.w*b3.x;
    acc[0][1] += a0.x*b0.y + a0.y*b1.y + a0.z*b2.y + a0.w*b3.y;
    acc[0][2] += a0.x*b0.z + a0.y*b1.z + a0.z*b2.z + a0.w*b3.z;
    acc[0][3] += a0.x*b0.w + a0.y*b1.w + a0.z*b2.w + a0.w*b3.w;
    acc[1][0] += a1.x*b0.x + a1.y*b1.x + a1.z*b2.x + a1.w*b3.x;
    acc[1][1] += a1.x*b0.y + a1.y*b1.y + a1.z*b2.y + a1.w*b3.y;
    acc[1][2] += a1.x*b0.z + a1.y*b1.z + a1.z*b2.z + a1.w*b3.z;
    acc[1][3] += a1.x*b0.w + a1.y*b1.w + a1.z*b2.w + a1.w*b3.w;
    acc[2][0] += a2.x*b0.x + a2.y*b1.x + a2.z*b2.x + a2.w*b3.x;
    acc[2][1] += a2.x*b0.y + a2.y*b1.y + a2.z*b2.y + a2.w*b3.y;
    acc[2][2] += a2.x*b0.z + a2.y*b1.z + a2.z*b2.z + a2.w*b3.z;
    acc[2][3] += a2.x*b0.w + a2.y*b1.w + a2.z*b2.w + a2.w*b3.w;
    acc[3][0] += a3.x*b0.x + a3.y*b1.x + a3.z*b2.x + a3.w*b3.x;
    acc[3][1] += a3.x*b0.y + a3.y*b1.y + a3.z*b2.y + a3.w*b3.y;
    acc[3][2] += a3.x*b0.z + a3.y*b1.z + a3.z*b2.z + a3.w*b3.z;
    acc[3][3] += a3.x*b0.w + a3.y*b1.w + a3.z*b2.w + a3.w*b3.w;
  }

  float sj[4], tj[4];
#pragma unroll
  for (int j = 0; j < 4; ++j) {
    int c = col0 + (tx << 2) + j;
    float s = gg[c] * rsqrtf(vv[c] + EPS);
    sj[j] = s;
    tj[j] = be[c] + (bb[c] - mm[c]) * s;
  }
#pragma unroll
  for (int i = 0; i < 4; ++i) {
    int row = row0 + ty * 4 + i;
    if (row < N) {
      float4 o;
      o.x = fmaxf(fmaf(acc[i][0], sj[0], tj[0]), 0.f);
      o.y = fmaxf(fmaf(acc[i][1], sj[1], tj[1]), 0.f);
      o.z = fmaxf(fmaf(acc[i][2], sj[2], tj[2]), 0.f);
      o.w = fmaxf(fmaf(acc[i][3], sj[3], tj[3]), 0.f);
      *(float4*)&out[(size_t)row * 128 + col0 + (tx << 2)] = o;
    }
  }
}

// ---------------- pooling + classifier ----------------
__global__ void k_hist_batch(const int* __restrict__ batch, int* __restrict__ cnt, int N) {
  int i = blockIdx.x * blockDim.x + threadIdx.x;
  if (i < N) atomicAdd(&cnt[batch[i]], 1);
}

__global__ __launch_bounds__(128) void k_pool(
    const float* __restrict__ h, const int* __restrict__ batch,
    float* __restrict__ pooled, int N) {
  int f = threadIdx.x;
  int n0 = blockIdx.x * 128;
  int nEnd = min(n0 + 128, N);
  float acc = 0.f;
  int cur = -1;
  for (int nn = n0; nn < nEnd; ++nn) {
    int g = batch[nn];
    if (g != cur) {
      if (cur >= 0) atomicAdd(&pooled[cur * 128 + f], acc);
      cur = g;
      acc = 0.f;
    }
    acc += h[(size_t)nn * 128 + f];
  }
  if (cur >= 0) atomicAdd(&pooled[cur * 128 + f], acc);
}

__global__ __launch_bounds__(64) void k_cls(
    const float* __restrict__ pooled, const int* __restrict__ cnt,
    const float* __restrict__ Wc1, const float* __restrict__ bc1,
    const float* __restrict__ Wc2, const float* __restrict__ bc2,
    float* __restrict__ out, int G) {
  __shared__ float pm[128];
  __shared__ float hid[64];
  int g = blockIdx.x, t = threadIdx.x;
  float invc = 1.f / fmaxf((float)cnt[g], 1.f);
  pm[t]      = pooled[g * 128 + t] * invc;
  pm[t + 64] = pooled[g * 128 + 64 + t] * invc;
  __syncthreads();
  float a = bc1[t];
#pragma unroll 8
  for (int k = 0; k < 128; ++k) a = fmaf(pm[k], Wc1[k * 64 + t], a);
  hid[t] = fmaxf(a, 0.f);
  __syncthreads();
  if (t < 10) {
    float a2 = bc2[t];
#pragma unroll
    for (int j = 0; j < 64; ++j) a2 = fmaf(hid[j], Wc2[j * 10 + t], a2);
    out[g * 10 + t] = a2;
  }
}

extern "C" void kernel_launch(void* const* d_in, const int* in_sizes, int n_in,
                              void* d_out, int out_size, void* d_ws, size_t ws_size,
                              hipStream_t stream) {
  const float* x   = (const float*)d_in[0];
  const int*   ei  = (const int*)d_in[1];
  const int* batch = (const int*)d_in[2];
  const float* W1 = (const float*)d_in[3];
  const float* b1 = (const float*)d_in[4];
  const float* g1 = (const float*)d_in[5];
  const float* be1 = (const float*)d_in[6];
  const float* m1 = (const float*)d_in[7];
  const float* v1 = (const float*)d_in[8];
  const float* W2 = (const float*)d_in[9];
  const float* b2 = (const float*)d_in[10];
  const float* g2 = (const float*)d_in[11];
  const float* be2 = (const float*)d_in[12];
  const float* m2 = (const float*)d_in[13];
  const float* v2 = (const float*)d_in[14];
  const float* W3 = (const float*)d_in[15];
  const float* b3 = (const float*)d_in[16];
  const float* g3 = (const float*)d_in[17];
  const float* be3 = (const float*)d_in[18];
  const float* m3 = (const float*)d_in[19];
  const float* v3 = (const float*)d_in[20];
  const float* Wc1 = (const float*)d_in[21];
  const float* bc1 = (const float*)d_in[22];
  const float* Wc2 = (const float*)d_in[23];
  const float* bc2 = (const float*)d_in[24];

  const int N = in_sizes[0] / 13;
  const int E = in_sizes[1] / 2;
  const int G = out_size / 10;
  const int* src = ei;
  const int* dst = ei + E;

  char* ws = (char*)d_ws;
  size_t off = 0;
  auto alloc = [&](size_t bytes) {
    char* p = ws + off;
    off = (off + bytes + 255) & ~(size_t)255;
    return p;
  };
  int*   deg    = (int*)  alloc((size_t)N * 4);
  float* dis    = (float*)alloc((size_t)N * 4);
  int*   offs   = (int*)  alloc((size_t)(N + 1) * 4);
  int*   curp   = (int*)  alloc((size_t)N * 4);
  const int nb  = (N + 255) / 256;
  int*   bsum   = (int*)  alloc((size_t)nb * 4);
  int*   bexc   = (int*)  alloc((size_t)nb * 4);
  int2*  csr    = (int2*) alloc((size_t)E * 8);
  float* bufA   = (float*)alloc((size_t)N * 128 * 4);
  float* bufB   = (float*)alloc((size_t)N * 128 * 4);
  float* pooled = (float*)alloc((size_t)G * 128 * 4);
  int*   cntg   = (int*)  alloc((size_t)G * 4);
  float* x16 = bufA;  // [N,16] lives in bufA space (dead before bufA is rewritten)
  float* ax  = bufB;  // [N,16] lives in bufB space

  hipMemsetAsync(deg, 0, (size_t)N * 4, stream);
  hipMemsetAsync(pooled, 0, (size_t)G * 128 * 4, stream);
  hipMemsetAsync(cntg, 0, (size_t)G * 4, stream);

  k_hist<<<2048, 256, 0, stream>>>(dst, deg, E);
  k_dis<<<(N + 255) / 256, 256, 0, stream>>>(deg, dis, N);
  k_scan_block<<<nb, 256, 0, stream>>>(deg, offs, bsum, N);
  k_scan_bsum<<<1, 512, 0, stream>>>(bsum, bexc, nb);
  k_add_back<<<nb, 256, 0, stream>>>(offs, bexc, curp, N, E);
  k_fill<<<2048, 256, 0, stream>>>(src, dst, dis, curp, csr, E);

  k_padx<<<(N * 16 + 255) / 256, 256, 0, stream>>>(x, x16, N);
  k_agg16<<<(N + 3) / 4, 64, 0, stream>>>(x16, csr, offs, dis, ax, N);
  k_gemm1<<<(N * 128 + 255) / 256, 256, 0, stream>>>(ax, W1, b1, g1, be1, m1, v1, bufA, N);

  const int gemmGrid = ((N + 63) / 64) * 2;
  k_agg128<<<(N + 3) / 4, 256, 0, stream>>>(bufA, csr, offs, dis, bufB, N);
  k_gemm_hh<<<gemmGrid, 256, 0, stream>>>(bufB, W2, b2, g2, be2, m2, v2, bufA, N);
  k_agg128<<<(N + 3) / 4, 256, 0, stream>>>(bufA, csr, offs, dis, bufB, N);
  k_gemm_hh<<<gemmGrid, 256, 0, stream>>>(bufB, W3, b3, g3, be3, m3, v3, bufA, N);

  k_hist_batch<<<(N + 255) / 256, 256, 0, stream>>>(batch, cntg, N);
  k_pool<<<(N + 127) / 128, 128, 0, stream>>>(bufA, batch, pooled, N);
  k_cls<<<G, 64, 0, stream>>>(pooled, cntg, Wc1, bc1, Wc2, bc2, (float*)d_out, G);
}

// Round 5
// 720.500 us; speedup vs baseline: 1.6661x; 1.1685x over previous
//
#include <hip/hip_runtime.h>
#include <hip/hip_bf16.h>

#define EPS 1e-5f

typedef unsigned short u16;
typedef unsigned int u32;

// ---- bf16 helpers (RNE encode, shift decode) ----
__device__ __forceinline__ u32 f2bf(float f) {
  u32 u = __float_as_uint(f);
  return (u + 0x7FFFu + ((u >> 16) & 1u)) >> 16;
}
__device__ __forceinline__ u32 pack2bf(float lo, float hi) {
  return f2bf(lo) | (f2bf(hi) << 16);
}
__device__ __forceinline__ float4 bf4(uint2 u) {
  float4 r;
  r.x = __uint_as_float(u.x << 16);
  r.y = __uint_as_float(u.x & 0xFFFF0000u);
  r.z = __uint_as_float(u.y << 16);
  r.w = __uint_as_float(u.y & 0xFFFF0000u);
  return r;
}

// ---------------- CSR build ----------------
__global__ void k_hist(const int* __restrict__ dst, int* __restrict__ cnt, int E) {
  for (int e = blockIdx.x * blockDim.x + threadIdx.x; e < E; e += gridDim.x * blockDim.x)
    atomicAdd(&cnt[dst[e]], 1);
}

__global__ void k_dis(const int* __restrict__ cnt, float* __restrict__ dis, int N) {
  int i = blockIdx.x * blockDim.x + threadIdx.x;
  if (i < N) dis[i] = rsqrtf((float)cnt[i] + 1.0f);
}

__global__ void k_scan_block(const int* __restrict__ in, int* __restrict__ out,
                             int* __restrict__ bsum, int N) {
  __shared__ int tmp[256];
  int lid = threadIdx.x;
  int i = blockIdx.x * 256 + lid;
  int v = (i < N) ? in[i] : 0;
  tmp[lid] = v;
  __syncthreads();
  for (int off = 1; off < 256; off <<= 1) {
    int t = (lid >= off) ? tmp[lid - off] : 0;
    __syncthreads();
    tmp[lid] += t;
    __syncthreads();
  }
  if (i < N) out[i] = tmp[lid] - v;            // exclusive within block
  if (lid == 255) bsum[blockIdx.x] = tmp[255];
}

__global__ void k_scan_bsum(const int* __restrict__ bsum, int* __restrict__ bexc, int nb) {
  __shared__ int tmp[512];
  int lid = threadIdx.x;
  int v = (lid < nb) ? bsum[lid] : 0;
  tmp[lid] = v;
  __syncthreads();
  for (int off = 1; off < 512; off <<= 1) {
    int t = (lid >= off) ? tmp[lid - off] : 0;
    __syncthreads();
    tmp[lid] += t;
    __syncthreads();
  }
  if (lid < nb) bexc[lid] = tmp[lid] - v;      // exclusive
}

__global__ void k_add_back(int* __restrict__ offs, const int* __restrict__ bexc,
                           int* __restrict__ cur, int N, int E) {
  int i = blockIdx.x * 256 + threadIdx.x;
  if (i < N) {
    int v = offs[i] + bexc[blockIdx.x];
    offs[i] = v;
    cur[i] = v;
  }
  if (i == 0) offs[N] = E;
}

// packed CSR entry: .x = src node, .y = float bits of edge weight
__global__ void k_fill(const int* __restrict__ src, const int* __restrict__ dst,
                       const float* __restrict__ dis, int* __restrict__ cur,
                       int2* __restrict__ csr, int E) {
  for (int e = blockIdx.x * blockDim.x + threadIdx.x; e < E; e += gridDim.x * blockDim.x) {
    int s = src[e], d = dst[e];
    int p = atomicAdd(&cur[d], 1);
    float w = dis[s] * dis[d];
    csr[p] = make_int2(s, __float_as_int(w));
  }
}

// ---------------- layer 1 (aggregate 13(->16) features, then K=13 GEMM) ----------------
__global__ void k_padx(const float* __restrict__ x, float* __restrict__ x16, int N) {
  int i = blockIdx.x * blockDim.x + threadIdx.x;
  if (i >= N * 16) return;
  int n = i >> 4, f = i & 15;
  x16[i] = (f < 13) ? x[n * 13 + f] : 0.0f;
}

__global__ __launch_bounds__(64) void k_agg16(
    const float* __restrict__ h, const int2* __restrict__ csr,
    const int* __restrict__ offs, const float* __restrict__ dis,
    float* __restrict__ out, int N) {
  int node = (blockIdx.x << 2) + (threadIdx.x >> 4);
  int f = threadIdx.x & 15;
  if (node >= N) return;
  float dn = dis[node];
  float a0 = h[(size_t)node * 16 + f] * dn * dn;
  float a1 = 0.f, a2 = 0.f, a3 = 0.f;
  int beg = offs[node], end = offs[node + 1];
  int i = beg;
  for (; i + 4 <= end; i += 4) {
    int2 e0 = csr[i + 0], e1 = csr[i + 1], e2 = csr[i + 2], e3 = csr[i + 3];
    float v0 = h[(size_t)e0.x * 16 + f];
    float v1 = h[(size_t)e1.x * 16 + f];
    float v2 = h[(size_t)e2.x * 16 + f];
    float v3 = h[(size_t)e3.x * 16 + f];
    a0 = fmaf(v0, __int_as_float(e0.y), a0);
    a1 = fmaf(v1, __int_as_float(e1.y), a1);
    a2 = fmaf(v2, __int_as_float(e2.y), a2);
    a3 = fmaf(v3, __int_as_float(e3.y), a3);
  }
  for (; i < end; ++i) {
    int2 e = csr[i];
    a0 = fmaf(h[(size_t)e.x * 16 + f], __int_as_float(e.y), a0);
  }
  out[(size_t)node * 16 + f] = (a0 + a1) + (a2 + a3);
}

// K=13 GEMM + BN/ReLU, bf16 packed output. One thread -> 2 channels.
__global__ __launch_bounds__(256) void k_gemm1(
    const float* __restrict__ ax, const float* __restrict__ W1,
    const float* __restrict__ bb, const float* __restrict__ gg,
    const float* __restrict__ be, const float* __restrict__ mm,
    const float* __restrict__ vv, u32* __restrict__ outb, int N) {
  int idx = blockIdx.x * 256 + threadIdx.x;
  if (idx >= N * 64) return;
  int node = idx >> 6, cp = idx & 63;
  int c0 = cp * 2, c1 = c0 + 1;
  float s0 = gg[c0] * rsqrtf(vv[c0] + EPS);
  float t0 = be[c0] + (bb[c0] - mm[c0]) * s0;
  float s1 = gg[c1] * rsqrtf(vv[c1] + EPS);
  float t1 = be[c1] + (bb[c1] - mm[c1]) * s1;
  float acc0 = 0.f, acc1 = 0.f;
#pragma unroll
  for (int k = 0; k < 13; ++k) {
    float av = ax[(size_t)node * 16 + k];
    acc0 = fmaf(av, W1[k * 128 + c0], acc0);
    acc1 = fmaf(av, W1[k * 128 + c1], acc1);
  }
  float o0 = fmaxf(fmaf(acc0, s0, t0), 0.f);
  float o1 = fmaxf(fmaf(acc1, s1, t1), 0.f);
  outb[(size_t)node * 64 + cp] = pack2bf(o0, o1);
}

// ---- 128-feature aggregation over bf16 h: 1 wave/node, 2 edges/wave, 8 pair-steps ----
__global__ __launch_bounds__(256) void k_agg128(
    const u16* __restrict__ hb, const int2* __restrict__ csr,
    const int* __restrict__ offs, const float* __restrict__ dis,
    float* __restrict__ out, int N) {
  int node = (blockIdx.x << 2) + (threadIdx.x >> 6);
  if (node >= N) return;
  const int lane = threadIdx.x & 63;
  const int half = lane >> 5;     // 0: edge A of pair, 1: edge B
  const int q = lane & 31;        // uint2 slot = features 4q..4q+3
  const uint2* __restrict__ h2p = (const uint2*)hb;
  float dn = dis[node];
  int beg = offs[node], end = offs[node + 1];

  // self term (lanes 0-31 carry it; upper half weight 0)
  float4 sv = bf4(h2p[(size_t)node * 32 + q]);
  float wsf = half ? 0.f : dn * dn;
  float4 a0 = make_float4(sv.x * wsf, sv.y * wsf, sv.z * wsf, sv.w * wsf);
  float4 z = make_float4(0.f, 0.f, 0.f, 0.f);
  float4 a1 = z, a2 = z, a3 = z, a4 = z, a5 = z, a6 = z, a7 = z;

  int i = beg;
  for (; i + 16 <= end; i += 16) {      // 8 pairs = 16 edges in flight
    int2 e0 = csr[i +  0 + half];
    int2 e1 = csr[i +  2 + half];
    int2 e2 = csr[i +  4 + half];
    int2 e3 = csr[i +  6 + half];
    int2 e4 = csr[i +  8 + half];
    int2 e5 = csr[i + 10 + half];
    int2 e6 = csr[i + 12 + half];
    int2 e7 = csr[i + 14 + half];
    uint2 u0 = h2p[(size_t)e0.x * 32 + q];
    uint2 u1 = h2p[(size_t)e1.x * 32 + q];
    uint2 u2 = h2p[(size_t)e2.x * 32 + q];
    uint2 u3 = h2p[(size_t)e3.x * 32 + q];
    uint2 u4 = h2p[(size_t)e4.x * 32 + q];
    uint2 u5 = h2p[(size_t)e5.x * 32 + q];
    uint2 u6 = h2p[(size_t)e6.x * 32 + q];
    uint2 u7 = h2p[(size_t)e7.x * 32 + q];
    float w0 = __int_as_float(e0.y), w1 = __int_as_float(e1.y);
    float w2 = __int_as_float(e2.y), w3 = __int_as_float(e3.y);
    float w4 = __int_as_float(e4.y), w5 = __int_as_float(e5.y);
    float w6 = __int_as_float(e6.y), w7 = __int_as_float(e7.y);
    float4 v0 = bf4(u0), v1 = bf4(u1), v2 = bf4(u2), v3 = bf4(u3);
    float4 v4 = bf4(u4), v5 = bf4(u5), v6 = bf4(u6), v7 = bf4(u7);
    a0.x = fmaf(v0.x, w0, a0.x); a0.y = fmaf(v0.y, w0, a0.y);
    a0.z = fmaf(v0.z, w0, a0.z); a0.w = fmaf(v0.w, w0, a0.w);
    a1.x = fmaf(v1.x, w1, a1.x); a1.y = fmaf(v1.y, w1, a1.y);
    a1.z = fmaf(v1.z, w1, a1.z); a1.w = fmaf(v1.w, w1, a1.w);
    a2.x = fmaf(v2.x, w2, a2.x); a2.y = fmaf(v2.y, w2, a2.y);
    a2.z = fmaf(v2.z, w2, a2.z); a2.w = fmaf(v2.w, w2, a2.w);
    a3.x = fmaf(v3.x, w3, a3.x); a3.y = fmaf(v3.y, w3, a3.y);
    a3.z = fmaf(v3.z, w3, a3.z); a3.w = fmaf(v3.w, w3, a3.w);
    a4.x = fmaf(v4.x, w4, a4.x); a4.y = fmaf(v4.y, w4, a4.y);
    a4.z = fmaf(v4.z, w4, a4.z); a4.w = fmaf(v4.w, w4, a4.w);
    a5.x = fmaf(v5.x, w5, a5.x); a5.y = fmaf(v5.y, w5, a5.y);
    a5.z = fmaf(v5.z, w5, a5.z); a5.w = fmaf(v5.w, w5, a5.w);
    a6.x = fmaf(v6.x, w6, a6.x); a6.y = fmaf(v6.y, w6, a6.y);
    a6.z = fmaf(v6.z, w6, a6.z); a6.w = fmaf(v6.w, w6, a6.w);
    a7.x = fmaf(v7.x, w7, a7.x); a7.y = fmaf(v7.y, w7, a7.y);
    a7.z = fmaf(v7.z, w7, a7.z); a7.w = fmaf(v7.w, w7, a7.w);
  }
  for (; i < end; i += 2) {             // remaining pairs (possibly ragged)
    int j = i + half;
    int jc = (j < end) ? j : (end - 1);
    int2 e = csr[jc];
    float w = (j < end) ? __int_as_float(e.y) : 0.f;
    float4 v = bf4(h2p[(size_t)e.x * 32 + q]);
    a0.x = fmaf(v.x, w, a0.x); a0.y = fmaf(v.y, w, a0.y);
    a0.z = fmaf(v.z, w, a0.z); a0.w = fmaf(v.w, w, a0.w);
  }

  float4 r;
  r.x = ((a0.x + a1.x) + (a2.x + a3.x)) + ((a4.x + a5.x) + (a6.x + a7.x));
  r.y = ((a0.y + a1.y) + (a2.y + a3.y)) + ((a4.y + a5.y) + (a6.y + a7.y));
  r.z = ((a0.z + a1.z) + (a2.z + a3.z)) + ((a4.z + a5.z) + (a6.z + a7.z));
  r.w = ((a0.w + a1.w) + (a2.w + a3.w)) + ((a4.w + a5.w) + (a6.w + a7.w));
  r.x += __shfl_xor(r.x, 32, 64);
  r.y += __shfl_xor(r.y, 32, 64);
  r.z += __shfl_xor(r.z, 32, 64);
  r.w += __shfl_xor(r.w, 32, 64);
  if (half == 0)
    ((float4*)out)[(size_t)node * 32 + q] = r;
}

// ------- H x H fp32 GEMM (64x64 tile, 4x4/thread) + BN/ReLU; fp32 or bf16 out -------
template <bool OB>
__global__ __launch_bounds__(256) void k_gemm_hh(
    const float* __restrict__ A, const float* __restrict__ W,
    const float* __restrict__ bb, const float* __restrict__ gg,
    const float* __restrict__ be, const float* __restrict__ mm,
    const float* __restrict__ vv, float* __restrict__ outf,
    u32* __restrict__ outb, int N) {
  __shared__ float a_lds[64 * 128];   // A tile, k-group XOR-swizzled
  __shared__ float w_lds[128 * 64];   // W column tile
  const int tid = threadIdx.x;
  const int bc = blockIdx.x & 1;
  const int br = blockIdx.x >> 1;
  const int row0 = br * 64, col0 = bc * 64;

  for (int i = tid; i < 2048; i += 256) {       // 64 rows x 32 float4
    int r = i >> 5;
    int s = i & 31;
    int ss = s ^ ((r >> 2) & 3);
    float4 v = make_float4(0.f, 0.f, 0.f, 0.f);
    int row = row0 + r;
    if (row < N) v = *(const float4*)&A[(size_t)row * 128 + (s << 2)];
    *(float4*)&a_lds[r * 128 + (ss << 2)] = v;
  }
  for (int i = tid; i < 2048; i += 256) {       // 128 rows x 16 float4
    int k = i >> 4;
    int c4 = (i & 15) << 2;
    *(float4*)&w_lds[k * 64 + c4] = *(const float4*)&W[k * 128 + col0 + c4];
  }
  __syncthreads();

  const int tx = tid & 15, ty = tid >> 4;
  float acc[4][4] = {};
#pragma unroll 4
  for (int kq = 0; kq < 32; ++kq) {
    const int k = kq << 2;
    const int ss = kq ^ (ty & 3);
    float4 a0 = *(const float4*)&a_lds[(ty * 4 + 0) * 128 + (ss << 2)];
    float4 a1 = *(const float4*)&a_lds[(ty * 4 + 1) * 128 + (ss << 2)];
    float4 a2 = *(const float4*)&a_lds[(ty * 4 + 2) * 128 + (ss << 2)];
    float4 a3 = *(const float4*)&a_lds[(ty * 4 + 3) * 128 + (ss << 2)];
    float4 b0 = *(const float4*)&w_lds[(k + 0) * 64 + (tx << 2)];
    float4 b1 = *(const float4*)&w_lds[(k + 1) * 64 + (tx << 2)];
    float4 b2 = *(const float4*)&w_lds[(k + 2) * 64 + (tx << 2)];
    float4 b3 = *(const float4*)&w_lds[(k + 3) * 64 + (tx << 2)];

    acc[0][0] += a0.x*b0.x + a0.y*b1.x + a0.z*b2.x + a0.w*b3.x;
    acc[0][1] += a0.x*b0.y + a0.y*b1.y + a0.z*b2.y + a0.w*b3.y;
    acc[0][2] += a0.x*b0.z + a0.y*b1.z + a0.z*b2.z + a0.w*b3.z;
    acc[0][3] += a0.x*b0.w + a0.y*b1.w + a0.z*b2.w + a0.w*b3.w;
    acc[1][0] += a1.x*b0.x + a1.y*b1.x + a1.z*b2.x + a1.w*b3.x;
    acc[1][1] += a1.x*b0.y + a1.y*b1.y + a1.z*b2.y + a1.w*b3.y;
    acc[1][2] += a1.x*b0.z + a1.y*b1.z + a1.z*b2.z + a1.w*b3.z;
    acc[1][3] += a1.x*b0.w + a1.y*b1.w + a1.z*b2.w + a1.w*b3.w;
    acc[2][0] += a2.x*b0.x + a2.y*b1.x + a2.z*b2.x + a2.w*b3.x;
    acc[2][1] += a2.x*b0.y + a2.y*b1.y + a2.z*b2.y + a2.w*b3.y;
    acc[2][2] += a2.x*b0.z + a2.y*b1.z + a2.z*b2.z + a2.w*b3.z;
    acc[2][3] += a2.x*b0.w + a2.y*b1.w + a2.z*b2.w + a2.w*b3.w;
    acc[3][0] += a3.x*b0.x + a3.y*b1.x + a3.z*b2.x + a3.w*b3.x;
    acc[3][1] += a3.x*b0.y + a3.y*b1.y + a3.z*b2.y + a3.w*b3.y;
    acc[3][2] += a3.x*b0.z + a3.y*b1.z + a3.z*b2.z + a3.w*b3.z;
    acc[3][3] += a3.x*b0.w + a3.y*b1.w + a3.z*b2.w + a3.w*b3.w;
  }

  float sj[4], tj[4];
#pragma unroll
  for (int j = 0; j < 4; ++j) {
    int c = col0 + (tx << 2) + j;
    float s = gg[c] * rsqrtf(vv[c] + EPS);
    sj[j] = s;
    tj[j] = be[c] + (bb[c] - mm[c]) * s;
  }
#pragma unroll
  for (int i = 0; i < 4; ++i) {
    int row = row0 + ty * 4 + i;
    if (row < N) {
      float4 o;
      o.x = fmaxf(fmaf(acc[i][0], sj[0], tj[0]), 0.f);
      o.y = fmaxf(fmaf(acc[i][1], sj[1], tj[1]), 0.f);
      o.z = fmaxf(fmaf(acc[i][2], sj[2], tj[2]), 0.f);
      o.w = fmaxf(fmaf(acc[i][3], sj[3], tj[3]), 0.f);
      if (OB) {
        uint2 p;
        p.x = pack2bf(o.x, o.y);
        p.y = pack2bf(o.z, o.w);
        ((uint2*)outb)[(size_t)row * 32 + ((col0 + (tx << 2)) >> 2)] = p;
      } else {
        *(float4*)&outf[(size_t)row * 128 + col0 + (tx << 2)] = o;
      }
    }
  }
}

// ---------------- pooling + classifier ----------------
// batch is sorted: count per graph via binary search (no atomics).
__global__ void k_cnt_batch(const int* __restrict__ batch, int* __restrict__ cnt,
                            int N, int G) {
  int g = blockIdx.x * blockDim.x + threadIdx.x;
  if (g >= G) return;
  int lo = 0, hi = N;
  while (lo < hi) { int m = (lo + hi) >> 1; if (batch[m] < g) lo = m + 1; else hi = m; }
  int lb = lo;
  lo = 0; hi = N;
  while (lo < hi) { int m = (lo + hi) >> 1; if (batch[m] <= g) lo = m + 1; else hi = m; }
  cnt[g] = lo - lb;
}

__global__ __launch_bounds__(128) void k_pool(
    const float* __restrict__ h, const int* __restrict__ batch,
    float* __restrict__ pooled, int N) {
  int f = threadIdx.x;
  int n0 = blockIdx.x * 128;
  int nEnd = min(n0 + 128, N);
  float acc = 0.f;
  int cur = -1;
  for (int nn = n0; nn < nEnd; ++nn) {
    int g = batch[nn];
    if (g != cur) {
      if (cur >= 0) atomicAdd(&pooled[cur * 128 + f], acc);
      cur = g;
      acc = 0.f;
    }
    acc += h[(size_t)nn * 128 + f];
  }
  if (cur >= 0) atomicAdd(&pooled[cur * 128 + f], acc);
}

__global__ __launch_bounds__(64) void k_cls(
    const float* __restrict__ pooled, const int* __restrict__ cnt,
    const float* __restrict__ Wc1, const float* __restrict__ bc1,
    const float* __restrict__ Wc2, const float* __restrict__ bc2,
    float* __restrict__ out, int G) {
  __shared__ float pm[128];
  __shared__ float hid[64];
  int g = blockIdx.x, t = threadIdx.x;
  float invc = 1.f / fmaxf((float)cnt[g], 1.f);
  pm[t]      = pooled[g * 128 + t] * invc;
  pm[t + 64] = pooled[g * 128 + 64 + t] * invc;
  __syncthreads();
  float a = bc1[t];
#pragma unroll 8
  for (int k = 0; k < 128; ++k) a = fmaf(pm[k], Wc1[k * 64 + t], a);
  hid[t] = fmaxf(a, 0.f);
  __syncthreads();
  if (t < 10) {
    float a2 = bc2[t];
#pragma unroll
    for (int j = 0; j < 64; ++j) a2 = fmaf(hid[j], Wc2[j * 10 + t], a2);
    out[g * 10 + t] = a2;
  }
}

extern "C" void kernel_launch(void* const* d_in, const int* in_sizes, int n_in,
                              void* d_out, int out_size, void* d_ws, size_t ws_size,
                              hipStream_t stream) {
  const float* x   = (const float*)d_in[0];
  const int*   ei  = (const int*)d_in[1];
  const int* batch = (const int*)d_in[2];
  const float* W1 = (const float*)d_in[3];
  const float* b1 = (const float*)d_in[4];
  const float* g1 = (const float*)d_in[5];
  const float* be1 = (const float*)d_in[6];
  const float* m1 = (const float*)d_in[7];
  const float* v1 = (const float*)d_in[8];
  const float* W2 = (const float*)d_in[9];
  const float* b2 = (const float*)d_in[10];
  const float* g2 = (const float*)d_in[11];
  const float* be2 = (const float*)d_in[12];
  const float* m2 = (const float*)d_in[13];
  const float* v2 = (const float*)d_in[14];
  const float* W3 = (const float*)d_in[15];
  const float* b3 = (const float*)d_in[16];
  const float* g3 = (const float*)d_in[17];
  const float* be3 = (const float*)d_in[18];
  const float* m3 = (const float*)d_in[19];
  const float* v3 = (const float*)d_in[20];
  const float* Wc1 = (const float*)d_in[21];
  const float* bc1 = (const float*)d_in[22];
  const float* Wc2 = (const float*)d_in[23];
  const float* bc2 = (const float*)d_in[24];

  const int N = in_sizes[0] / 13;
  const int E = in_sizes[1] / 2;
  const int G = out_size / 10;
  const int* src = ei;
  const int* dst = ei + E;

  char* ws = (char*)d_ws;
  size_t off = 0;
  auto alloc = [&](size_t bytes) {
    char* p = ws + off;
    off = (off + bytes + 255) & ~(size_t)255;
    return p;
  };
  int*   deg    = (int*)  alloc((size_t)N * 4);
  float* dis    = (float*)alloc((size_t)N * 4);
  int*   offs   = (int*)  alloc((size_t)(N + 1) * 4);
  int*   curp   = (int*)  alloc((size_t)N * 4);
  const int nb  = (N + 255) / 256;
  int*   bsum   = (int*)  alloc((size_t)nb * 4);
  int*   bexc   = (int*)  alloc((size_t)nb * 4);
  int2*  csr    = (int2*) alloc((size_t)E * 8);
  u16*   hbf    = (u16*)  alloc((size_t)N * 128 * 2);   // bf16 h1 then h2
  float* aggB   = (float*)alloc((size_t)N * 128 * 4);   // ax first, then agg output
  float* bufF   = (float*)alloc((size_t)N * 128 * 4);   // x16 first, then fp32 h3
  float* pooled = (float*)alloc((size_t)G * 128 * 4);
  int*   cntg   = (int*)  alloc((size_t)G * 4);
  float* x16 = bufF;   // [N,16]
  float* ax  = aggB;   // [N,16]

  hipMemsetAsync(deg, 0, (size_t)N * 4, stream);
  hipMemsetAsync(pooled, 0, (size_t)G * 128 * 4, stream);

  k_hist<<<2048, 256, 0, stream>>>(dst, deg, E);
  k_dis<<<(N + 255) / 256, 256, 0, stream>>>(deg, dis, N);
  k_scan_block<<<nb, 256, 0, stream>>>(deg, offs, bsum, N);
  k_scan_bsum<<<1, 512, 0, stream>>>(bsum, bexc, nb);
  k_add_back<<<nb, 256, 0, stream>>>(offs, bexc, curp, N, E);
  k_fill<<<2048, 256, 0, stream>>>(src, dst, dis, curp, csr, E);

  k_padx<<<(N * 16 + 255) / 256, 256, 0, stream>>>(x, x16, N);
  k_agg16<<<(N + 3) / 4, 64, 0, stream>>>(x16, csr, offs, dis, ax, N);
  k_gemm1<<<(N * 64 + 255) / 256, 256, 0, stream>>>(ax, W1, b1, g1, be1, m1, v1,
                                                    (u32*)hbf, N);

  const int gemmGrid = ((N + 63) / 64) * 2;
  k_agg128<<<(N + 3) / 4, 256, 0, stream>>>(hbf, csr, offs, dis, aggB, N);
  k_gemm_hh<true><<<gemmGrid, 256, 0, stream>>>(aggB, W2, b2, g2, be2, m2, v2,
                                                nullptr, (u32*)hbf, N);
  k_agg128<<<(N + 3) / 4, 256, 0, stream>>>(hbf, csr, offs, dis, aggB, N);
  k_gemm_hh<false><<<gemmGrid, 256, 0, stream>>>(aggB, W3, b3, g3, be3, m3, v3,
                                                 bufF, nullptr, N);

  k_cnt_batch<<<(G + 255) / 256, 256, 0, stream>>>(batch, cntg, N, G);
  k_pool<<<(N + 127) / 128, 128, 0, stream>>>(bufF, batch, pooled, N);
  k_cls<<<G, 64, 0, stream>>>(pooled, cntg, Wc1, bc1, Wc2, bc2, (float*)d_out, G);
}

// Round 6
// 640.413 us; speedup vs baseline: 1.8744x; 1.1251x over previous
//
#include <hip/hip_runtime.h>
#include <hip/hip_bf16.h>

#define EPS 1e-5f

typedef unsigned short u16;
typedef unsigned int u32;
typedef __attribute__((ext_vector_type(8))) short bf16x8;
typedef __attribute__((ext_vector_type(4))) float f32x4;

// ---- bf16 helpers (RNE encode, shift decode) ----
__device__ __forceinline__ u32 f2bf(float f) {
  u32 u = __float_as_uint(f);
  return (u + 0x7FFFu + ((u >> 16) & 1u)) >> 16;
}
__device__ __forceinline__ u32 pack2bf(float lo, float hi) {
  return f2bf(lo) | (f2bf(hi) << 16);
}
__device__ __forceinline__ float4 bf4(uint2 u) {
  float4 r;
  r.x = __uint_as_float(u.x << 16);
  r.y = __uint_as_float(u.x & 0xFFFF0000u);
  r.z = __uint_as_float(u.y << 16);
  r.w = __uint_as_float(u.y & 0xFFFF0000u);
  return r;
}

// ---------------- CSR build: histogram + per-edge rank ----------------
__global__ void k_hist_rank(const int* __restrict__ dst, int* __restrict__ cnt,
                            int* __restrict__ rank, int E) {
  int i = blockIdx.x * blockDim.x + threadIdx.x;
  int i4 = i << 2;
  if (i4 + 3 < E) {
    int d0 = dst[i4], d1 = dst[i4 + 1], d2 = dst[i4 + 2], d3 = dst[i4 + 3];
    int r0 = atomicAdd(&cnt[d0], 1);
    int r1 = atomicAdd(&cnt[d1], 1);
    int r2 = atomicAdd(&cnt[d2], 1);
    int r3 = atomicAdd(&cnt[d3], 1);
    rank[i4] = r0; rank[i4 + 1] = r1; rank[i4 + 2] = r2; rank[i4 + 3] = r3;
  } else {
    for (int e = i4; e < E; ++e) rank[e] = atomicAdd(&cnt[dst[e]], 1);
  }
}

__global__ void k_dis(const int* __restrict__ cnt, float* __restrict__ dis, int N) {
  int i = blockIdx.x * blockDim.x + threadIdx.x;
  if (i < N) dis[i] = rsqrtf((float)cnt[i] + 1.0f);
}

__global__ void k_scan_block(const int* __restrict__ in, int* __restrict__ out,
                             int* __restrict__ bsum, int N) {
  __shared__ int tmp[256];
  int lid = threadIdx.x;
  int i = blockIdx.x * 256 + lid;
  int v = (i < N) ? in[i] : 0;
  tmp[lid] = v;
  __syncthreads();
  for (int off = 1; off < 256; off <<= 1) {
    int t = (lid >= off) ? tmp[lid - off] : 0;
    __syncthreads();
    tmp[lid] += t;
    __syncthreads();
  }
  if (i < N) out[i] = tmp[lid] - v;            // exclusive within block
  if (lid == 255) bsum[blockIdx.x] = tmp[255];
}

__global__ void k_scan_bsum(const int* __restrict__ bsum, int* __restrict__ bexc, int nb) {
  __shared__ int tmp[512];
  int lid = threadIdx.x;
  int v = (lid < nb) ? bsum[lid] : 0;
  tmp[lid] = v;
  __syncthreads();
  for (int off = 1; off < 512; off <<= 1) {
    int t = (lid >= off) ? tmp[lid - off] : 0;
    __syncthreads();
    tmp[lid] += t;
    __syncthreads();
  }
  if (lid < nb) bexc[lid] = tmp[lid] - v;      // exclusive
}

__global__ void k_add_back(int* __restrict__ offs, const int* __restrict__ bexc,
                           int N, int E) {
  int i = blockIdx.x * 256 + threadIdx.x;
  if (i < N) offs[i] += bexc[blockIdx.x];
  if (i == 0) offs[N] = E;
}

// slot = offs[dst] + rank  (no atomic; scatter store is fire-and-forget)
__global__ void k_fill_rank(const int* __restrict__ src, const int* __restrict__ dst,
                            const int* __restrict__ rank, const int* __restrict__ offs,
                            int* __restrict__ csr, int E) {
  int i = blockIdx.x * blockDim.x + threadIdx.x;
  int i4 = i << 2;
  if (i4 + 3 < E) {
    int s0 = src[i4], s1 = src[i4 + 1], s2 = src[i4 + 2], s3 = src[i4 + 3];
    int d0 = dst[i4], d1 = dst[i4 + 1], d2 = dst[i4 + 2], d3 = dst[i4 + 3];
    int r0 = rank[i4], r1 = rank[i4 + 1], r2 = rank[i4 + 2], r3 = rank[i4 + 3];
    int p0 = offs[d0] + r0;
    int p1 = offs[d1] + r1;
    int p2 = offs[d2] + r2;
    int p3 = offs[d3] + r3;
    csr[p0] = s0; csr[p1] = s1; csr[p2] = s2; csr[p3] = s3;
  } else {
    for (int e = i4; e < E; ++e) csr[offs[dst[e]] + rank[e]] = src[e];
  }
}

// ---------------- W prep: split-transpose to bf16 hi/lo + BN scale fold ----------------
__global__ void k_prep_w(const float* __restrict__ W2, const float* __restrict__ W3,
                         const float* __restrict__ b2, const float* __restrict__ g2,
                         const float* __restrict__ be2, const float* __restrict__ m2,
                         const float* __restrict__ v2,
                         const float* __restrict__ b3, const float* __restrict__ g3,
                         const float* __restrict__ be3, const float* __restrict__ m3,
                         const float* __restrict__ v3,
                         u16* __restrict__ Wht2, u16* __restrict__ Wlt2,
                         u16* __restrict__ Wht3, u16* __restrict__ Wlt3,
                         float* __restrict__ sc2, float* __restrict__ tc2,
                         float* __restrict__ sc3, float* __restrict__ tc3) {
  int idx = blockIdx.x * 256 + threadIdx.x;     // 0..32767
  int layer = idx >> 14;
  int e = idx & 16383;
  int c = e >> 7, k = e & 127;
  const float* W = layer ? W3 : W2;
  float w = W[k * 128 + c];                     // transpose read
  u32 h = f2bf(w);
  float l = w - __uint_as_float(h << 16);
  u16* Wh = layer ? Wht3 : Wht2;
  u16* Wl = layer ? Wlt3 : Wlt2;
  Wh[e] = (u16)h;                               // [c][k] layout
  Wl[e] = (u16)f2bf(l);
  if (e < 128) {
    int ch = e;
    const float* gg = layer ? g3 : g2;  const float* vv = layer ? v3 : v2;
    const float* be = layer ? be3 : be2; const float* mm = layer ? m3 : m2;
    const float* bb = layer ? b3 : b2;
    float s = gg[ch] * rsqrtf(vv[ch] + EPS);
    (layer ? sc3 : sc2)[ch] = s;
    (layer ? tc3 : tc2)[ch] = be[ch] + (bb[ch] - mm[ch]) * s;
  }
}

// ---------------- layer 1 ----------------
// xs = dis[n] * x (padded 13->16)
__global__ void k_padx_scale(const float* __restrict__ x, const float* __restrict__ dis,
                             float* __restrict__ xs, int N) {
  int i = blockIdx.x * blockDim.x + threadIdx.x;
  if (i >= N * 16) return;
  int n = i >> 4, f = i & 15;
  xs[i] = (f < 13) ? x[n * 13 + f] * dis[n] : 0.0f;
}

// agg[d] = dis[d] * (sum_{s in N(d)} xs[s] + xs[d])
__global__ __launch_bounds__(64) void k_agg16(
    const float* __restrict__ xs, const int* __restrict__ csr,
    const int* __restrict__ offs, const float* __restrict__ dis,
    float* __restrict__ out, int N) {
  int node = (blockIdx.x << 2) + (threadIdx.x >> 4);
  int f = threadIdx.x & 15;
  if (node >= N) return;
  float a0 = xs[(size_t)node * 16 + f];   // self, weight 1
  float a1 = 0.f, a2 = 0.f, a3 = 0.f;
  int beg = offs[node], end = offs[node + 1];
  int i = beg;
  for (; i + 4 <= end; i += 4) {
    int s0 = csr[i], s1 = csr[i + 1], s2 = csr[i + 2], s3 = csr[i + 3];
    a0 += xs[(size_t)s0 * 16 + f];
    a1 += xs[(size_t)s1 * 16 + f];
    a2 += xs[(size_t)s2 * 16 + f];
    a3 += xs[(size_t)s3 * 16 + f];
  }
  for (; i < end; ++i) a0 += xs[(size_t)csr[i] * 16 + f];
  out[(size_t)node * 16 + f] = dis[node] * ((a0 + a1) + (a2 + a3));
}

// K=13 GEMM + BN/ReLU, writes hs1 = dis * h1 as packed bf16. One thread -> 2 channels.
__global__ __launch_bounds__(256) void k_gemm1(
    const float* __restrict__ ax, const float* __restrict__ W1,
    const float* __restrict__ bb, const float* __restrict__ gg,
    const float* __restrict__ be, const float* __restrict__ mm,
    const float* __restrict__ vv, const float* __restrict__ dis,
    u32* __restrict__ outb, int N) {
  int idx = blockIdx.x * 256 + threadIdx.x;
  if (idx >= N * 64) return;
  int node = idx >> 6, cp = idx & 63;
  int c0 = cp * 2, c1 = c0 + 1;
  float s0 = gg[c0] * rsqrtf(vv[c0] + EPS);
  float t0 = be[c0] + (bb[c0] - mm[c0]) * s0;
  float s1 = gg[c1] * rsqrtf(vv[c1] + EPS);
  float t1 = be[c1] + (bb[c1] - mm[c1]) * s1;
  float acc0 = 0.f, acc1 = 0.f;
#pragma unroll
  for (int k = 0; k < 13; ++k) {
    float av = ax[(size_t)node * 16 + k];
    acc0 = fmaf(av, W1[k * 128 + c0], acc0);
    acc1 = fmaf(av, W1[k * 128 + c1], acc1);
  }
  float dn = dis[node];
  float o0 = dn * fmaxf(fmaf(acc0, s0, t0), 0.f);
  float o1 = dn * fmaxf(fmaf(acc1, s1, t1), 0.f);
  outb[(size_t)node * 64 + cp] = pack2bf(o0, o1);
}

// ---- 128-feat aggregation over bf16 hs: 1 wave/node, 2 edges/wave, 8 pair-steps ----
// out = dis[d]*(sum hs[s] + hs[d]), written as split bf16 planes (Ah = hi, Al = residual)
__global__ __launch_bounds__(256) void k_agg128(
    const u16* __restrict__ hb, const int* __restrict__ csr,
    const int* __restrict__ offs, const float* __restrict__ dis,
    uint2* __restrict__ Ahp, uint2* __restrict__ Alp, int N) {
  int node = (blockIdx.x << 2) + (threadIdx.x >> 6);
  if (node >= N) return;
  const int lane = threadIdx.x & 63;
  const int half = lane >> 5;     // 0: edge A of pair, 1: edge B
  const int q = lane & 31;        // uint2 slot = features 4q..4q+3
  const uint2* __restrict__ h2p = (const uint2*)hb;
  float dn = dis[node];
  int beg = offs[node], end = offs[node + 1];

  // self term (weight 1, lanes 0-31 only)
  float4 sv = bf4(h2p[(size_t)node * 32 + q]);
  float wsf = half ? 0.f : 1.f;
  float4 a0 = make_float4(sv.x * wsf, sv.y * wsf, sv.z * wsf, sv.w * wsf);
  float4 z = make_float4(0.f, 0.f, 0.f, 0.f);
  float4 a1 = z, a2 = z, a3 = z, a4 = z, a5 = z, a6 = z, a7 = z;

  int i = beg;
  for (; i + 16 <= end; i += 16) {      // 8 pairs = 16 edges in flight
    int s0 = csr[i +  0 + half];
    int s1 = csr[i +  2 + half];
    int s2 = csr[i +  4 + half];
    int s3 = csr[i +  6 + half];
    int s4 = csr[i +  8 + half];
    int s5 = csr[i + 10 + half];
    int s6 = csr[i + 12 + half];
    int s7 = csr[i + 14 + half];
    uint2 u0 = h2p[(size_t)s0 * 32 + q];
    uint2 u1 = h2p[(size_t)s1 * 32 + q];
    uint2 u2 = h2p[(size_t)s2 * 32 + q];
    uint2 u3 = h2p[(size_t)s3 * 32 + q];
    uint2 u4 = h2p[(size_t)s4 * 32 + q];
    uint2 u5 = h2p[(size_t)s5 * 32 + q];
    uint2 u6 = h2p[(size_t)s6 * 32 + q];
    uint2 u7 = h2p[(size_t)s7 * 32 + q];
    float4 v0 = bf4(u0), v1 = bf4(u1), v2 = bf4(u2), v3 = bf4(u3);
    float4 v4 = bf4(u4), v5 = bf4(u5), v6 = bf4(u6), v7 = bf4(u7);
    a0.x += v0.x; a0.y += v0.y; a0.z += v0.z; a0.w += v0.w;
    a1.x += v1.x; a1.y += v1.y; a1.z += v1.z; a1.w += v1.w;
    a2.x += v2.x; a2.y += v2.y; a2.z += v2.z; a2.w += v2.w;
    a3.x += v3.x; a3.y += v3.y; a3.z += v3.z; a3.w += v3.w;
    a4.x += v4.x; a4.y += v4.y; a4.z += v4.z; a4.w += v4.w;
    a5.x += v5.x; a5.y += v5.y; a5.z += v5.z; a5.w += v5.w;
    a6.x += v6.x; a6.y += v6.y; a6.z += v6.z; a6.w += v6.w;
    a7.x += v7.x; a7.y += v7.y; a7.z += v7.z; a7.w += v7.w;
  }
  for (; i < end; i += 2) {             // remaining pairs (possibly ragged)
    int j = i + half;
    int jc = (j < end) ? j : (end - 1);
    int s = csr[jc];
    float wt = (j < end) ? 1.f : 0.f;
    float4 v = bf4(h2p[(size_t)s * 32 + q]);
    a0.x = fmaf(v.x, wt, a0.x); a0.y = fmaf(v.y, wt, a0.y);
    a0.z = fmaf(v.z, wt, a0.z); a0.w = fmaf(v.w, wt, a0.w);
  }

  float4 r;
  r.x = ((a0.x + a1.x) + (a2.x + a3.x)) + ((a4.x + a5.x) + (a6.x + a7.x));
  r.y = ((a0.y + a1.y) + (a2.y + a3.y)) + ((a4.y + a5.y) + (a6.y + a7.y));
  r.z = ((a0.z + a1.z) + (a2.z + a3.z)) + ((a4.z + a5.z) + (a6.z + a7.z));
  r.w = ((a0.w + a1.w) + (a2.w + a3.w)) + ((a4.w + a5.w) + (a6.w + a7.w));
  r.x += __shfl_xor(r.x, 32, 64);
  r.y += __shfl_xor(r.y, 32, 64);
  r.z += __shfl_xor(r.z, 32, 64);
  r.w += __shfl_xor(r.w, 32, 64);
  if (half == 0) {
    r.x *= dn; r.y *= dn; r.z *= dn; r.w *= dn;
    u32 hx = f2bf(r.x), hy = f2bf(r.y), hz = f2bf(r.z), hw = f2bf(r.w);
    uint2 ph = make_uint2(hx | (hy << 16), hz | (hw << 16));
    float lx = r.x - __uint_as_float(hx << 16);
    float ly = r.y - __uint_as_float(hy << 16);
    float lz = r.z - __uint_as_float(hz << 16);
    float lw = r.w - __uint_as_float(hw << 16);
    uint2 pl = make_uint2(pack2bf(lx, ly), pack2bf(lz, lw));
    Ahp[(size_t)node * 32 + q] = ph;
    Alp[(size_t)node * 32 + q] = pl;
  }
}

// ---- H x H GEMM via bf16x3-split MFMA (16x16x32), no LDS, 32 rows/wave ----
// C = (Ah+Al)(Wh+Wl) ~= Ah*Wh + Al*Wh + Ah*Wl ; BN/ReLU epilogue.
// OB: write hs = dis*h as bf16; else write fp32 h.
template <bool OB>
__global__ __launch_bounds__(256) void k_gemm_mfma(
    const u16* __restrict__ Ah, const u16* __restrict__ Al,
    const u16* __restrict__ Wht, const u16* __restrict__ Wlt,
    const float* __restrict__ sc, const float* __restrict__ tc,
    const float* __restrict__ dis,
    float* __restrict__ outf, u16* __restrict__ outb, int N) {
  const int lane = threadIdx.x & 63;
  const int wv = threadIdx.x >> 6;            // wave 0..3
  const int r0 = blockIdx.x * 128 + wv * 32;  // this wave: rows r0..r0+31
  const int lr = lane & 15;
  const int kg = lane >> 4;                   // k-group 0..3

  // A fragments: 2 row-tiles x 4 k-steps, hi and lo planes
  bf16x8 ahf[2][4], alf[2][4];
#pragma unroll
  for (int rt = 0; rt < 2; ++rt) {
    int row = min(r0 + rt * 16 + lr, N - 1);
    const bf16x8* pAh = (const bf16x8*)(Ah + (size_t)row * 128 + kg * 8);
    const bf16x8* pAl = (const bf16x8*)(Al + (size_t)row * 128 + kg * 8);
#pragma unroll
    for (int ks = 0; ks < 4; ++ks) {
      ahf[rt][ks] = pAh[ks * 4];
      alf[rt][ks] = pAl[ks * 4];
    }
  }
  float dr[2][4];
  if (OB) {
#pragma unroll
    for (int rt = 0; rt < 2; ++rt)
#pragma unroll
      for (int j = 0; j < 4; ++j)
        dr[rt][j] = dis[min(r0 + rt * 16 + kg * 4 + j, N - 1)];
  }

#pragma unroll
  for (int ct = 0; ct < 8; ++ct) {
    int c = ct * 16 + lr;
    const bf16x8* pBh = (const bf16x8*)(Wht + (size_t)c * 128 + kg * 8);
    const bf16x8* pBl = (const bf16x8*)(Wlt + (size_t)c * 128 + kg * 8);
    bf16x8 bh[4], bl[4];
#pragma unroll
    for (int ks = 0; ks < 4; ++ks) { bh[ks] = pBh[ks * 4]; bl[ks] = pBl[ks * 4]; }
    float s = sc[c], t = tc[c];
#pragma unroll
    for (int rt = 0; rt < 2; ++rt) {
      f32x4 acc = {0.f, 0.f, 0.f, 0.f};
#pragma unroll
      for (int ks = 0; ks < 4; ++ks) {
        acc = __builtin_amdgcn_mfma_f32_16x16x32_bf16(ahf[rt][ks], bh[ks], acc, 0, 0, 0);
        acc = __builtin_amdgcn_mfma_f32_16x16x32_bf16(alf[rt][ks], bh[ks], acc, 0, 0, 0);
        acc = __builtin_amdgcn_mfma_f32_16x16x32_bf16(ahf[rt][ks], bl[ks], acc, 0, 0, 0);
      }
      // C/D: col = lane&15, row = (lane>>4)*4 + j   [m89-verified]
#pragma unroll
      for (int j = 0; j < 4; ++j) {
        int row = r0 + rt * 16 + kg * 4 + j;
        if (row < N) {
          float o = fmaxf(fmaf(acc[j], s, t), 0.f);
          if (OB) {
            outb[(size_t)row * 128 + c] = (u16)f2bf(o * dr[rt][j]);
          } else {
            outf[(size_t)row * 128 + c] = o;
          }
        }
      }
    }
  }
}

// ---------------- pooling + classifier ----------------
__global__ void k_cnt_batch(const int* __restrict__ batch, int* __restrict__ cnt,
                            int N, int G) {
  int g = blockIdx.x * blockDim.x + threadIdx.x;
  if (g >= G) return;
  int lo = 0, hi = N;
  while (lo < hi) { int m = (lo + hi) >> 1; if (batch[m] < g) lo = m + 1; else hi = m; }
  int lb = lo;
  lo = 0; hi = N;
  while (lo < hi) { int m = (lo + hi) >> 1; if (batch[m] <= g) lo = m + 1; else hi = m; }
  cnt[g] = lo - lb;
}

__global__ __launch_bounds__(128) void k_pool(
    const float* __restrict__ h, const int* __restrict__ batch,
    float* __restrict__ pooled, int N) {
  int f = threadIdx.x;
  int n0 = blockIdx.x * 128;
  int nEnd = min(n0 + 128, N);
  float acc = 0.f;
  int cur = -1;
  for (int nn = n0; nn < nEnd; ++nn) {
    int g = batch[nn];
    if (g != cur) {
      if (cur >= 0) atomicAdd(&pooled[cur * 128 + f], acc);
      cur = g;
      acc = 0.f;
    }
    acc += h[(size_t)nn * 128 + f];
  }
  if (cur >= 0) atomicAdd(&pooled[cur * 128 + f], acc);
}

__global__ __launch_bounds__(64) void k_cls(
    const float* __restrict__ pooled, const int* __restrict__ cnt,
    const float* __restrict__ Wc1, const float* __restrict__ bc1,
    const float* __restrict__ Wc2, const float* __restrict__ bc2,
    float* __restrict__ out, int G) {
  __shared__ float pm[128];
  __shared__ float hid[64];
  int g = blockIdx.x, t = threadIdx.x;
  float invc = 1.f / fmaxf((float)cnt[g], 1.f);
  pm[t]      = pooled[g * 128 + t] * invc;
  pm[t + 64] = pooled[g * 128 + 64 + t] * invc;
  __syncthreads();
  float a = bc1[t];
#pragma unroll 8
  for (int k = 0; k < 128; ++k) a = fmaf(pm[k], Wc1[k * 64 + t], a);
  hid[t] = fmaxf(a, 0.f);
  __syncthreads();
  if (t < 10) {
    float a2 = bc2[t];
#pragma unroll
    for (int j = 0; j < 64; ++j) a2 = fmaf(hid[j], Wc2[j * 10 + t], a2);
    out[g * 10 + t] = a2;
  }
}

extern "C" void kernel_launch(void* const* d_in, const int* in_sizes, int n_in,
                              void* d_out, int out_size, void* d_ws, size_t ws_size,
                              hipStream_t stream) {
  const float* x   = (const float*)d_in[0];
  const int*   ei  = (const int*)d_in[1];
  const int* batch = (const int*)d_in[2];
  const float* W1 = (const float*)d_in[3];
  const float* b1 = (const float*)d_in[4];
  const float* g1 = (const float*)d_in[5];
  const float* be1 = (const float*)d_in[6];
  const float* m1 = (const float*)d_in[7];
  const float* v1 = (const float*)d_in[8];
  const float* W2 = (const float*)d_in[9];
  const float* b2 = (const float*)d_in[10];
  const float* g2 = (const float*)d_in[11];
  const float* be2 = (const float*)d_in[12];
  const float* m2 = (const float*)d_in[13];
  const float* v2 = (const float*)d_in[14];
  const float* W3 = (const float*)d_in[15];
  const float* b3 = (const float*)d_in[16];
  const float* g3 = (const float*)d_in[17];
  const float* be3 = (const float*)d_in[18];
  const float* m3 = (const float*)d_in[19];
  const float* v3 = (const float*)d_in[20];
  const float* Wc1 = (const float*)d_in[21];
  const float* bc1 = (const float*)d_in[22];
  const float* Wc2 = (const float*)d_in[23];
  const float* bc2 = (const float*)d_in[24];

  const int N = in_sizes[0] / 13;
  const int E = in_sizes[1] / 2;
  const int G = out_size / 10;
  const int* src = ei;
  const int* dst = ei + E;

  char* ws = (char*)d_ws;
  size_t off = 0;
  auto alloc = [&](size_t bytes) {
    char* p = ws + off;
    off = (off + bytes + 255) & ~(size_t)255;
    return p;
  };
  int*   deg    = (int*)  alloc((size_t)N * 4);
  float* dis    = (float*)alloc((size_t)N * 4);
  int*   offs   = (int*)  alloc((size_t)(N + 1) * 4);
  const int nb  = (N + 255) / 256;
  int*   bsum   = (int*)  alloc((size_t)nb * 4);
  int*   bexc   = (int*)  alloc((size_t)nb * 4);
  int*   rank   = (int*)  alloc((size_t)E * 4);
  int*   csr    = (int*)  alloc((size_t)E * 4);
  u16*   hbf    = (u16*)  alloc((size_t)N * 128 * 2);   // hs (dis*h) bf16
  u16*   Ahp    = (u16*)  alloc((size_t)N * 128 * 2);   // agg out hi
  u16*   Alp    = (u16*)  alloc((size_t)N * 128 * 2);   // agg out lo residual
  float* bufF   = (float*)alloc((size_t)N * 128 * 4);   // xs first, then fp32 h3
  u16*   Wht2   = (u16*)  alloc(16384 * 2);
  u16*   Wlt2   = (u16*)  alloc(16384 * 2);
  u16*   Wht3   = (u16*)  alloc(16384 * 2);
  u16*   Wlt3   = (u16*)  alloc(16384 * 2);
  float* sc2    = (float*)alloc(128 * 4);
  float* tc2    = (float*)alloc(128 * 4);
  float* sc3    = (float*)alloc(128 * 4);
  float* tc3    = (float*)alloc(128 * 4);
  float* pooled = (float*)alloc((size_t)G * 128 * 4);
  int*   cntg   = (int*)  alloc((size_t)G * 4);
  float* xs = bufF;          // [N,16] alias (dead before bufF reused for h3)
  float* ax = (float*)Ahp;   // [N,16] alias (consumed before agg128 writes Ahp)

  hipMemsetAsync(deg, 0, (size_t)N * 4, stream);
  hipMemsetAsync(pooled, 0, (size_t)G * 128 * 4, stream);

  k_prep_w<<<128, 256, 0, stream>>>(W2, W3, b2, g2, be2, m2, v2, b3, g3, be3, m3, v3,
                                    Wht2, Wlt2, Wht3, Wlt3, sc2, tc2, sc3, tc3);

  const int nE4 = (E + 3) / 4;
  k_hist_rank<<<(nE4 + 255) / 256, 256, 0, stream>>>(dst, deg, rank, E);
  k_dis<<<(N + 255) / 256, 256, 0, stream>>>(deg, dis, N);
  k_scan_block<<<nb, 256, 0, stream>>>(deg, offs, bsum, N);
  k_scan_bsum<<<1, 512, 0, stream>>>(bsum, bexc, nb);
  k_add_back<<<nb, 256, 0, stream>>>(offs, bexc, N, E);
  k_fill_rank<<<(nE4 + 255) / 256, 256, 0, stream>>>(src, dst, rank, offs, csr, E);

  k_padx_scale<<<(N * 16 + 255) / 256, 256, 0, stream>>>(x, dis, xs, N);
  k_agg16<<<(N + 3) / 4, 64, 0, stream>>>(xs, csr, offs, dis, ax, N);
  k_gemm1<<<(N * 64 + 255) / 256, 256, 0, stream>>>(ax, W1, b1, g1, be1, m1, v1, dis,
                                                    (u32*)hbf, N);

  const int gemmGrid = (N + 127) / 128;
  k_agg128<<<(N + 3) / 4, 256, 0, stream>>>(hbf, csr, offs, dis,
                                            (uint2*)Ahp, (uint2*)Alp, N);
  k_gemm_mfma<true><<<gemmGrid, 256, 0, stream>>>(Ahp, Alp, Wht2, Wlt2, sc2, tc2, dis,
                                                  nullptr, hbf, N);
  k_agg128<<<(N + 3) / 4, 256, 0, stream>>>(hbf, csr, offs, dis,
                                            (uint2*)Ahp, (uint2*)Alp, N);
  k_gemm_mfma<false><<<gemmGrid, 256, 0, stream>>>(Ahp, Alp, Wht3, Wlt3, sc3, tc3, dis,
                                                   bufF, nullptr, N);

  k_cnt_batch<<<(G + 255) / 256, 256, 0, stream>>>(batch, cntg, N, G);
  k_pool<<<(N + 127) / 128, 128, 0, stream>>>(bufF, batch, pooled, N);
  k_cls<<<G, 64, 0, stream>>>(pooled, cntg, Wc1, bc1, Wc2, bc2, (float*)d_out, G);
}

// Round 7
// 586.876 us; speedup vs baseline: 2.0454x; 1.0912x over previous
//
#include <hip/hip_runtime.h>
#include <hip/hip_bf16.h>

#define EPS 1e-5f

typedef unsigned short u16;
typedef unsigned int u32;
typedef __attribute__((ext_vector_type(8))) short bf16x8;
typedef __attribute__((ext_vector_type(4))) float f32x4;

// ---- bf16 helpers (RNE encode, shift decode) ----
__device__ __forceinline__ u32 f2bf(float f) {
  u32 u = __float_as_uint(f);
  return (u + 0x7FFFu + ((u >> 16) & 1u)) >> 16;
}
__device__ __forceinline__ u32 pack2bf(float lo, float hi) {
  return f2bf(lo) | (f2bf(hi) << 16);
}

// accumulate 2 packed bf16 into float2 accumulator
__device__ __forceinline__ void dacc(float2& a, u32 u) {
  a.x += __uint_as_float(u << 16);
  a.y += __uint_as_float(u & 0xFFFF0000u);
}

// ---------------- CSR build: histogram + per-edge rank ----------------
__global__ void k_hist_rank(const int* __restrict__ dst, int* __restrict__ cnt,
                            int* __restrict__ rank, int E) {
  int i = blockIdx.x * blockDim.x + threadIdx.x;
  int i4 = i << 2;
  if (i4 + 3 < E) {
    int d0 = dst[i4], d1 = dst[i4 + 1], d2 = dst[i4 + 2], d3 = dst[i4 + 3];
    int r0 = atomicAdd(&cnt[d0], 1);
    int r1 = atomicAdd(&cnt[d1], 1);
    int r2 = atomicAdd(&cnt[d2], 1);
    int r3 = atomicAdd(&cnt[d3], 1);
    rank[i4] = r0; rank[i4 + 1] = r1; rank[i4 + 2] = r2; rank[i4 + 3] = r3;
  } else {
    for (int e = i4; e < E; ++e) rank[e] = atomicAdd(&cnt[dst[e]], 1);
  }
}

// dis = rsqrt(deg+1); pdeg = deg rounded up to multiple of 4 (for padded CSR)
__global__ void k_dis_pdeg(const int* __restrict__ cnt, float* __restrict__ dis,
                           int* __restrict__ pdeg, int N) {
  int i = blockIdx.x * blockDim.x + threadIdx.x;
  if (i < N) {
    int d = cnt[i];
    dis[i] = rsqrtf((float)d + 1.0f);
    pdeg[i] = (d + 3) & ~3;
  }
}

__global__ void k_scan_block(const int* __restrict__ in, int* __restrict__ out,
                             int* __restrict__ bsum, int N) {
  __shared__ int tmp[256];
  int lid = threadIdx.x;
  int i = blockIdx.x * 256 + lid;
  int v = (i < N) ? in[i] : 0;
  tmp[lid] = v;
  __syncthreads();
  for (int off = 1; off < 256; off <<= 1) {
    int t = (lid >= off) ? tmp[lid - off] : 0;
    __syncthreads();
    tmp[lid] += t;
    __syncthreads();
  }
  if (i < N) out[i] = tmp[lid] - v;            // exclusive within block
  if (lid == 255) bsum[blockIdx.x] = tmp[255];
}

__global__ void k_scan_bsum(const int* __restrict__ bsum, int* __restrict__ bexc, int nb) {
  __shared__ int tmp[512];
  int lid = threadIdx.x;
  int v = (lid < nb) ? bsum[lid] : 0;
  tmp[lid] = v;
  __syncthreads();
  for (int off = 1; off < 512; off <<= 1) {
    int t = (lid >= off) ? tmp[lid - off] : 0;
    __syncthreads();
    tmp[lid] += t;
    __syncthreads();
  }
  if (lid < nb) bexc[lid] = tmp[lid] - v;      // exclusive
}

__global__ void k_add_back(int* __restrict__ offs, const int* __restrict__ bexc,
                           const int* __restrict__ bsum, int N, int nb) {
  int i = blockIdx.x * 256 + threadIdx.x;
  if (i < N) offs[i] += bexc[blockIdx.x];
  if (i == 0) offs[N] = bexc[nb - 1] + bsum[nb - 1];   // total padded count
}

// slot = offs[dst] + rank  (no atomic; scatter store is fire-and-forget)
__global__ void k_fill_rank(const int* __restrict__ src, const int* __restrict__ dst,
                            const int* __restrict__ rank, const int* __restrict__ offs,
                            int* __restrict__ csr, int E) {
  int i = blockIdx.x * blockDim.x + threadIdx.x;
  int i4 = i << 2;
  if (i4 + 3 < E) {
    int s0 = src[i4], s1 = src[i4 + 1], s2 = src[i4 + 2], s3 = src[i4 + 3];
    int d0 = dst[i4], d1 = dst[i4 + 1], d2 = dst[i4 + 2], d3 = dst[i4 + 3];
    int r0 = rank[i4], r1 = rank[i4 + 1], r2 = rank[i4 + 2], r3 = rank[i4 + 3];
    csr[offs[d0] + r0] = s0;
    csr[offs[d1] + r1] = s1;
    csr[offs[d2] + r2] = s2;
    csr[offs[d3] + r3] = s3;
  } else {
    for (int e = i4; e < E; ++e) csr[offs[dst[e]] + rank[e]] = src[e];
  }
}

// fill dummy slots [offs+deg, offs+pdeg) with node N (zero row)
__global__ void k_pad_fill(const int* __restrict__ deg, const int* __restrict__ offs,
                           int* __restrict__ csr, int N) {
  int n = blockIdx.x * blockDim.x + threadIdx.x;
  if (n >= N) return;
  int b = offs[n] + deg[n], e = offs[n + 1];
  for (int j = b; j < e; ++j) csr[j] = N;
}

// ---------------- W prep: split-transpose to bf16 hi/lo + BN scale fold ----------------
__global__ void k_prep_w(const float* __restrict__ W2, const float* __restrict__ W3,
                         const float* __restrict__ b2, const float* __restrict__ g2,
                         const float* __restrict__ be2, const float* __restrict__ m2,
                         const float* __restrict__ v2,
                         const float* __restrict__ b3, const float* __restrict__ g3,
                         const float* __restrict__ be3, const float* __restrict__ m3,
                         const float* __restrict__ v3,
                         u16* __restrict__ Wht2, u16* __restrict__ Wlt2,
                         u16* __restrict__ Wht3, u16* __restrict__ Wlt3,
                         float* __restrict__ sc2, float* __restrict__ tc2,
                         float* __restrict__ sc3, float* __restrict__ tc3) {
  int idx = blockIdx.x * 256 + threadIdx.x;     // 0..32767
  int layer = idx >> 14;
  int e = idx & 16383;
  int c = e >> 7, k = e & 127;
  const float* W = layer ? W3 : W2;
  float w = W[k * 128 + c];                     // transpose read
  u32 h = f2bf(w);
  float l = w - __uint_as_float(h << 16);
  u16* Wh = layer ? Wht3 : Wht2;
  u16* Wl = layer ? Wlt3 : Wlt2;
  Wh[e] = (u16)h;                               // [c][k] layout
  Wl[e] = (u16)f2bf(l);
  if (e < 128) {
    int ch = e;
    const float* gg = layer ? g3 : g2;  const float* vv = layer ? v3 : v2;
    const float* be = layer ? be3 : be2; const float* mm = layer ? m3 : m2;
    const float* bb = layer ? b3 : b2;
    float s = gg[ch] * rsqrtf(vv[ch] + EPS);
    (layer ? sc3 : sc2)[ch] = s;
    (layer ? tc3 : tc2)[ch] = be[ch] + (bb[ch] - mm[ch]) * s;
  }
}

// ---------------- layer 1 ----------------
// xs = dis[n] * x (padded 13->16); row N zeroed
__global__ void k_padx_scale(const float* __restrict__ x, const float* __restrict__ dis,
                             float* __restrict__ xs, int N) {
  int i = blockIdx.x * blockDim.x + threadIdx.x;
  if (i >= (N + 1) * 16) return;
  int n = i >> 4, f = i & 15;
  xs[i] = (n < N && f < 13) ? x[n * 13 + f] * dis[n] : 0.0f;
}

// agg[d] = dis[d] * (sum_{s in padded N(d)} xs[s] + xs[d]); exact 4-edge steps
__global__ __launch_bounds__(64) void k_agg16(
    const float* __restrict__ xs, const int* __restrict__ csr,
    const int* __restrict__ offs, const float* __restrict__ dis,
    float* __restrict__ out, int N) {
  int node = (blockIdx.x << 2) + (threadIdx.x >> 4);
  if (node >= N) return;
  int f = threadIdx.x & 15;
  float a0 = xs[(size_t)node * 16 + f];   // self, weight 1
  float a1 = 0.f, a2 = 0.f, a3 = 0.f;
  int beg = offs[node], end = offs[node + 1];
  for (int i = beg; i < end; i += 4) {
    int4 s4 = *(const int4*)(csr + i);
    a0 += xs[(size_t)s4.x * 16 + f];
    a1 += xs[(size_t)s4.y * 16 + f];
    a2 += xs[(size_t)s4.z * 16 + f];
    a3 += xs[(size_t)s4.w * 16 + f];
  }
  out[(size_t)node * 16 + f] = dis[node] * ((a0 + a1) + (a2 + a3));
}

// K=13 GEMM + BN/ReLU, writes hs1 = dis * h1 as packed bf16; row N zeroed.
__global__ __launch_bounds__(256) void k_gemm1(
    const float* __restrict__ ax, const float* __restrict__ W1,
    const float* __restrict__ bb, const float* __restrict__ gg,
    const float* __restrict__ be, const float* __restrict__ mm,
    const float* __restrict__ vv, const float* __restrict__ dis,
    u32* __restrict__ outb, int N) {
  int idx = blockIdx.x * 256 + threadIdx.x;
  if (idx >= (N + 1) * 64) return;
  int node = idx >> 6, cp = idx & 63;
  if (node == N) { outb[(size_t)node * 64 + cp] = 0u; return; }
  int c0 = cp * 2, c1 = c0 + 1;
  float s0 = gg[c0] * rsqrtf(vv[c0] + EPS);
  float t0 = be[c0] + (bb[c0] - mm[c0]) * s0;
  float s1 = gg[c1] * rsqrtf(vv[c1] + EPS);
  float t1 = be[c1] + (bb[c1] - mm[c1]) * s1;
  float acc0 = 0.f, acc1 = 0.f;
#pragma unroll
  for (int k = 0; k < 13; ++k) {
    float av = ax[(size_t)node * 16 + k];
    acc0 = fmaf(av, W1[k * 128 + c0], acc0);
    acc1 = fmaf(av, W1[k * 128 + c1], acc1);
  }
  float dn = dis[node];
  float o0 = dn * fmaxf(fmaf(acc0, s0, t0), 0.f);
  float o1 = dn * fmaxf(fmaf(acc1, s1, t1), 0.f);
  outb[(size_t)node * 64 + cp] = pack2bf(o0, o1);
}

// ---- 128-feat aggregation, quad scheme: 1 wave/node, 4 edges/step, uint4/lane ----
// out = dis[d]*(sum hs[s] + hs[d]) -> split bf16 planes Ah (hi) / Al (residual)
__global__ __launch_bounds__(256) void k_agg128(
    const u16* __restrict__ hb, const int* __restrict__ csr,
    const int* __restrict__ offs, const float* __restrict__ dis,
    uint4* __restrict__ Ahp, uint4* __restrict__ Alp, int N) {
  int node = (blockIdx.x << 2) + (threadIdx.x >> 6);
  if (node >= N) return;
  node = __builtin_amdgcn_readfirstlane(node);   // wave-uniform by construction
  const int lane = threadIdx.x & 63;
  const int qt = lane >> 4;      // edge slot within quad (0..3)
  const int q = lane & 15;       // uint4 slot = features 8q..8q+7
  const uint4* __restrict__ H = (const uint4*)hb;
  int beg = offs[node], end = offs[node + 1];    // multiple-of-4 segment

  float2 z2 = make_float2(0.f, 0.f);
  float2 aA0 = z2, aA1 = z2, aA2 = z2, aA3 = z2;
  float2 aB0 = z2, aB1 = z2, aB2 = z2, aB3 = z2;

  // self term (weight 1), qt==0 lanes only
  {
    uint4 su = H[(size_t)node * 16 + q];
    if (qt == 0) { dacc(aA0, su.x); dacc(aA1, su.y); dacc(aA2, su.z); dacc(aA3, su.w); }
  }

  int i = beg;
  for (; i + 8 <= end; i += 8) {     // 8 edges, 2 independent quad-streams
    int4 sA = *(const int4*)(csr + i);
    int4 sB = *(const int4*)(csr + i + 4);
    int ea = (qt == 0) ? sA.x : (qt == 1) ? sA.y : (qt == 2) ? sA.z : sA.w;
    int eb = (qt == 0) ? sB.x : (qt == 1) ? sB.y : (qt == 2) ? sB.z : sB.w;
    uint4 uA = H[(size_t)ea * 16 + q];
    uint4 uB = H[(size_t)eb * 16 + q];
    dacc(aA0, uA.x); dacc(aA1, uA.y); dacc(aA2, uA.z); dacc(aA3, uA.w);
    dacc(aB0, uB.x); dacc(aB1, uB.y); dacc(aB2, uB.z); dacc(aB3, uB.w);
  }
  if (i < end) {                     // exactly one remaining quad
    int4 sA = *(const int4*)(csr + i);
    int ea = (qt == 0) ? sA.x : (qt == 1) ? sA.y : (qt == 2) ? sA.z : sA.w;
    uint4 uA = H[(size_t)ea * 16 + q];
    dacc(aA0, uA.x); dacc(aA1, uA.y); dacc(aA2, uA.z); dacc(aA3, uA.w);
  }

  float r[8];
  r[0] = aA0.x + aB0.x; r[1] = aA0.y + aB0.y;
  r[2] = aA1.x + aB1.x; r[3] = aA1.y + aB1.y;
  r[4] = aA2.x + aB2.x; r[5] = aA2.y + aB2.y;
  r[6] = aA3.x + aB3.x; r[7] = aA3.y + aB3.y;
#pragma unroll
  for (int j = 0; j < 8; ++j) {
    r[j] += __shfl_xor(r[j], 16, 64);
    r[j] += __shfl_xor(r[j], 32, 64);
  }
  if (qt == 0) {
    float dn = dis[node];
    uint4 ph, pl;
    u32 hw[8];
#pragma unroll
    for (int j = 0; j < 8; ++j) { r[j] *= dn; hw[j] = f2bf(r[j]); }
    ph.x = hw[0] | (hw[1] << 16);
    ph.y = hw[2] | (hw[3] << 16);
    ph.z = hw[4] | (hw[5] << 16);
    ph.w = hw[6] | (hw[7] << 16);
    float l[8];
#pragma unroll
    for (int j = 0; j < 8; ++j) l[j] = r[j] - __uint_as_float(hw[j] << 16);
    pl.x = pack2bf(l[0], l[1]);
    pl.y = pack2bf(l[2], l[3]);
    pl.z = pack2bf(l[4], l[5]);
    pl.w = pack2bf(l[6], l[7]);
    Ahp[(size_t)node * 16 + q] = ph;
    Alp[(size_t)node * 16 + q] = pl;
  }
}

// ---- H x H GEMM via bf16x3-split MFMA (16x16x32), no LDS, 32 rows/wave ----
template <bool OB>
__global__ __launch_bounds__(256) void k_gemm_mfma(
    const u16* __restrict__ Ah, const u16* __restrict__ Al,
    const u16* __restrict__ Wht, const u16* __restrict__ Wlt,
    const float* __restrict__ sc, const float* __restrict__ tc,
    const float* __restrict__ dis,
    float* __restrict__ outf, u16* __restrict__ outb, int N) {
  const int lane = threadIdx.x & 63;
  const int wv = threadIdx.x >> 6;            // wave 0..3
  const int r0 = blockIdx.x * 128 + wv * 32;  // this wave: rows r0..r0+31
  const int lr = lane & 15;
  const int kg = lane >> 4;                   // k-group 0..3

  bf16x8 ahf[2][4], alf[2][4];
#pragma unroll
  for (int rt = 0; rt < 2; ++rt) {
    int row = min(r0 + rt * 16 + lr, N - 1);
    const bf16x8* pAh = (const bf16x8*)(Ah + (size_t)row * 128 + kg * 8);
    const bf16x8* pAl = (const bf16x8*)(Al + (size_t)row * 128 + kg * 8);
#pragma unroll
    for (int ks = 0; ks < 4; ++ks) {
      ahf[rt][ks] = pAh[ks * 4];
      alf[rt][ks] = pAl[ks * 4];
    }
  }
  float dr[2][4];
  if (OB) {
#pragma unroll
    for (int rt = 0; rt < 2; ++rt)
#pragma unroll
      for (int j = 0; j < 4; ++j)
        dr[rt][j] = dis[min(r0 + rt * 16 + kg * 4 + j, N - 1)];
  }

#pragma unroll
  for (int ct = 0; ct < 8; ++ct) {
    int c = ct * 16 + lr;
    const bf16x8* pBh = (const bf16x8*)(Wht + (size_t)c * 128 + kg * 8);
    const bf16x8* pBl = (const bf16x8*)(Wlt + (size_t)c * 128 + kg * 8);
    bf16x8 bh[4], bl[4];
#pragma unroll
    for (int ks = 0; ks < 4; ++ks) { bh[ks] = pBh[ks * 4]; bl[ks] = pBl[ks * 4]; }
    float s = sc[c], t = tc[c];
#pragma unroll
    for (int rt = 0; rt < 2; ++rt) {
      f32x4 acc = {0.f, 0.f, 0.f, 0.f};
#pragma unroll
      for (int ks = 0; ks < 4; ++ks) {
        acc = __builtin_amdgcn_mfma_f32_16x16x32_bf16(ahf[rt][ks], bh[ks], acc, 0, 0, 0);
        acc = __builtin_amdgcn_mfma_f32_16x16x32_bf16(alf[rt][ks], bh[ks], acc, 0, 0, 0);
        acc = __builtin_amdgcn_mfma_f32_16x16x32_bf16(ahf[rt][ks], bl[ks], acc, 0, 0, 0);
      }
      // C/D: col = lane&15, row = (lane>>4)*4 + j   [m89-verified]
#pragma unroll
      for (int j = 0; j < 4; ++j) {
        int row = r0 + rt * 16 + kg * 4 + j;
        if (row < N) {
          float o = fmaxf(fmaf(acc[j], s, t), 0.f);
          if (OB) {
            outb[(size_t)row * 128 + c] = (u16)f2bf(o * dr[rt][j]);
          } else {
            outf[(size_t)row * 128 + c] = o;
          }
        }
      }
    }
  }
}

// ---------------- pooling + classifier ----------------
__global__ void k_cnt_batch(const int* __restrict__ batch, int* __restrict__ cnt,
                            int N, int G) {
  int g = blockIdx.x * blockDim.x + threadIdx.x;
  if (g >= G) return;
  int lo = 0, hi = N;
  while (lo < hi) { int m = (lo + hi) >> 1; if (batch[m] < g) lo = m + 1; else hi = m; }
  int lb = lo;
  lo = 0; hi = N;
  while (lo < hi) { int m = (lo + hi) >> 1; if (batch[m] <= g) lo = m + 1; else hi = m; }
  cnt[g] = lo - lb;
}

__global__ __launch_bounds__(128) void k_pool(
    const float* __restrict__ h, const int* __restrict__ batch,
    float* __restrict__ pooled, int N) {
  int f = threadIdx.x;
  int n0 = blockIdx.x * 128;
  int nEnd = min(n0 + 128, N);
  float acc = 0.f;
  int cur = -1;
  for (int nn = n0; nn < nEnd; ++nn) {
    int g = batch[nn];
    if (g != cur) {
      if (cur >= 0) atomicAdd(&pooled[cur * 128 + f], acc);
      cur = g;
      acc = 0.f;
    }
    acc += h[(size_t)nn * 128 + f];
  }
  if (cur >= 0) atomicAdd(&pooled[cur * 128 + f], acc);
}

__global__ __launch_bounds__(64) void k_cls(
    const float* __restrict__ pooled, const int* __restrict__ cnt,
    const float* __restrict__ Wc1, const float* __restrict__ bc1,
    const float* __restrict__ Wc2, const float* __restrict__ bc2,
    float* __restrict__ out, int G) {
  __shared__ float pm[128];
  __shared__ float hid[64];
  int g = blockIdx.x, t = threadIdx.x;
  float invc = 1.f / fmaxf((float)cnt[g], 1.f);
  pm[t]      = pooled[g * 128 + t] * invc;
  pm[t + 64] = pooled[g * 128 + 64 + t] * invc;
  __syncthreads();
  float a = bc1[t];
#pragma unroll 8
  for (int k = 0; k < 128; ++k) a = fmaf(pm[k], Wc1[k * 64 + t], a);
  hid[t] = fmaxf(a, 0.f);
  __syncthreads();
  if (t < 10) {
    float a2 = bc2[t];
#pragma unroll
    for (int j = 0; j < 64; ++j) a2 = fmaf(hid[j], Wc2[j * 10 + t], a2);
    out[g * 10 + t] = a2;
  }
}

extern "C" void kernel_launch(void* const* d_in, const int* in_sizes, int n_in,
                              void* d_out, int out_size, void* d_ws, size_t ws_size,
                              hipStream_t stream) {
  const float* x   = (const float*)d_in[0];
  const int*   ei  = (const int*)d_in[1];
  const int* batch = (const int*)d_in[2];
  const float* W1 = (const float*)d_in[3];
  const float* b1 = (const float*)d_in[4];
  const float* g1 = (const float*)d_in[5];
  const float* be1 = (const float*)d_in[6];
  const float* m1 = (const float*)d_in[7];
  const float* v1 = (const float*)d_in[8];
  const float* W2 = (const float*)d_in[9];
  const float* b2 = (const float*)d_in[10];
  const float* g2 = (const float*)d_in[11];
  const float* be2 = (const float*)d_in[12];
  const float* m2 = (const float*)d_in[13];
  const float* v2 = (const float*)d_in[14];
  const float* W3 = (const float*)d_in[15];
  const float* b3 = (const float*)d_in[16];
  const float* g3 = (const float*)d_in[17];
  const float* be3 = (const float*)d_in[18];
  const float* m3 = (const float*)d_in[19];
  const float* v3 = (const float*)d_in[20];
  const float* Wc1 = (const float*)d_in[21];
  const float* bc1 = (const float*)d_in[22];
  const float* Wc2 = (const float*)d_in[23];
  const float* bc2 = (const float*)d_in[24];

  const int N = in_sizes[0] / 13;
  const int E = in_sizes[1] / 2;
  const int G = out_size / 10;
  const int* src = ei;
  const int* dst = ei + E;

  char* ws = (char*)d_ws;
  size_t off = 0;
  auto alloc = [&](size_t bytes) {
    char* p = ws + off;
    off = (off + bytes + 255) & ~(size_t)255;
    return p;
  };
  int*   deg    = (int*)  alloc((size_t)N * 4);
  float* dis    = (float*)alloc((size_t)N * 4);
  int*   pdeg   = (int*)  alloc((size_t)N * 4);
  int*   offs   = (int*)  alloc((size_t)(N + 1) * 4);
  const int nb  = (N + 255) / 256;
  int*   bsum   = (int*)  alloc((size_t)nb * 4);
  int*   bexc   = (int*)  alloc((size_t)nb * 4);
  int*   rank   = (int*)  alloc((size_t)E * 4);
  int*   csr    = (int*)  alloc(((size_t)E + 3 * (size_t)N + 8) * 4);
  u16*   hbf    = (u16*)  alloc((size_t)(N + 1) * 128 * 2);   // hs bf16, row N = 0
  u16*   Ahp    = (u16*)  alloc((size_t)N * 128 * 2);         // agg out hi
  u16*   Alp    = (u16*)  alloc((size_t)N * 128 * 2);         // agg out lo residual
  float* bufF   = (float*)alloc((size_t)(N + 1) * 128 * 4);   // xs first, then fp32 h3
  u16*   Wht2   = (u16*)  alloc(16384 * 2);
  u16*   Wlt2   = (u16*)  alloc(16384 * 2);
  u16*   Wht3   = (u16*)  alloc(16384 * 2);
  u16*   Wlt3   = (u16*)  alloc(16384 * 2);
  float* sc2    = (float*)alloc(128 * 4);
  float* tc2    = (float*)alloc(128 * 4);
  float* sc3    = (float*)alloc(128 * 4);
  float* tc3    = (float*)alloc(128 * 4);
  float* pooled = (float*)alloc((size_t)G * 128 * 4);
  int*   cntg   = (int*)  alloc((size_t)G * 4);
  float* xs = bufF;          // [(N+1),16] alias (dead before bufF reused for h3)
  float* ax = (float*)Ahp;   // [N,16] alias (consumed before agg128 writes Ahp)

  hipMemsetAsync(deg, 0, (size_t)N * 4, stream);
  hipMemsetAsync(pooled, 0, (size_t)G * 128 * 4, stream);

  k_prep_w<<<128, 256, 0, stream>>>(W2, W3, b2, g2, be2, m2, v2, b3, g3, be3, m3, v3,
                                    Wht2, Wlt2, Wht3, Wlt3, sc2, tc2, sc3, tc3);

  const int nE4 = (E + 3) / 4;
  k_hist_rank<<<(nE4 + 255) / 256, 256, 0, stream>>>(dst, deg, rank, E);
  k_dis_pdeg<<<(N + 255) / 256, 256, 0, stream>>>(deg, dis, pdeg, N);
  k_scan_block<<<nb, 256, 0, stream>>>(pdeg, offs, bsum, N);
  k_scan_bsum<<<1, 512, 0, stream>>>(bsum, bexc, nb);
  k_add_back<<<nb, 256, 0, stream>>>(offs, bexc, bsum, N, nb);
  k_fill_rank<<<(nE4 + 255) / 256, 256, 0, stream>>>(src, dst, rank, offs, csr, E);
  k_pad_fill<<<(N + 255) / 256, 256, 0, stream>>>(deg, offs, csr, N);

  k_padx_scale<<<((N + 1) * 16 + 255) / 256, 256, 0, stream>>>(x, dis, xs, N);
  k_agg16<<<(N + 3) / 4, 64, 0, stream>>>(xs, csr, offs, dis, ax, N);
  k_gemm1<<<((N + 1) * 64 + 255) / 256, 256, 0, stream>>>(ax, W1, b1, g1, be1, m1, v1,
                                                          dis, (u32*)hbf, N);

  const int gemmGrid = (N + 127) / 128;
  k_agg128<<<(N + 3) / 4, 256, 0, stream>>>(hbf, csr, offs, dis,
                                            (uint4*)Ahp, (uint4*)Alp, N);
  k_gemm_mfma<true><<<gemmGrid, 256, 0, stream>>>(Ahp, Alp, Wht2, Wlt2, sc2, tc2, dis,
                                                  nullptr, hbf, N);
  k_agg128<<<(N + 3) / 4, 256, 0, stream>>>(hbf, csr, offs, dis,
                                            (uint4*)Ahp, (uint4*)Alp, N);
  k_gemm_mfma<false><<<gemmGrid, 256, 0, stream>>>(Ahp, Alp, Wht3, Wlt3, sc3, tc3, dis,
                                                   bufF, nullptr, N);

  k_cnt_batch<<<(G + 255) / 256, 256, 0, stream>>>(batch, cntg, N, G);
  k_pool<<<(N + 127) / 128, 128, 0, stream>>>(bufF, batch, pooled, N);
  k_cls<<<G, 64, 0, stream>>>(pooled, cntg, Wc1, bc1, Wc2, bc2, (float*)d_out, G);
}

// Round 8
// 540.347 us; speedup vs baseline: 2.2215x; 1.0861x over previous
//
#include <hip/hip_runtime.h>
#include <hip/hip_bf16.h>

#define EPS 1e-5f

typedef unsigned short u16;
typedef unsigned int u32;
typedef __attribute__((ext_vector_type(8))) short bf16x8;
typedef __attribute__((ext_vector_type(4))) float f32x4;

// ---- bf16 helpers (RNE encode, shift decode) ----
__device__ __forceinline__ u32 f2bf(float f) {
  u32 u = __float_as_uint(f);
  return (u + 0x7FFFu + ((u >> 16) & 1u)) >> 16;
}
__device__ __forceinline__ u32 pack2bf(float lo, float hi) {
  return f2bf(lo) | (f2bf(hi) << 16);
}

// accumulate 2 packed bf16 into float2 accumulator
__device__ __forceinline__ void dacc(float2& a, u32 u) {
  a.x += __uint_as_float(u << 16);
  a.y += __uint_as_float(u & 0xFFFF0000u);
}

// ---------------- CSR build: histogram + per-edge rank ----------------
__global__ void k_hist_rank(const int* __restrict__ dst, int* __restrict__ cnt,
                            int* __restrict__ rank, int E) {
  int i = blockIdx.x * blockDim.x + threadIdx.x;
  int i4 = i << 2;
  if (i4 + 3 < E) {
    int d0 = dst[i4], d1 = dst[i4 + 1], d2 = dst[i4 + 2], d3 = dst[i4 + 3];
    int r0 = atomicAdd(&cnt[d0], 1);
    int r1 = atomicAdd(&cnt[d1], 1);
    int r2 = atomicAdd(&cnt[d2], 1);
    int r3 = atomicAdd(&cnt[d3], 1);
    rank[i4] = r0; rank[i4 + 1] = r1; rank[i4 + 2] = r2; rank[i4 + 3] = r3;
  } else {
    for (int e = i4; e < E; ++e) rank[e] = atomicAdd(&cnt[dst[e]], 1);
  }
}

// dis = rsqrt(deg+1); pdeg = deg rounded up to multiple of 4 (for padded CSR)
__global__ void k_dis_pdeg(const int* __restrict__ cnt, float* __restrict__ dis,
                           int* __restrict__ pdeg, int N) {
  int i = blockIdx.x * blockDim.x + threadIdx.x;
  if (i < N) {
    int d = cnt[i];
    dis[i] = rsqrtf((float)d + 1.0f);
    pdeg[i] = (d + 3) & ~3;
  }
}

__global__ void k_scan_block(const int* __restrict__ in, int* __restrict__ out,
                             int* __restrict__ bsum, int N) {
  __shared__ int tmp[256];
  int lid = threadIdx.x;
  int i = blockIdx.x * 256 + lid;
  int v = (i < N) ? in[i] : 0;
  tmp[lid] = v;
  __syncthreads();
  for (int off = 1; off < 256; off <<= 1) {
    int t = (lid >= off) ? tmp[lid - off] : 0;
    __syncthreads();
    tmp[lid] += t;
    __syncthreads();
  }
  if (i < N) out[i] = tmp[lid] - v;            // exclusive within block
  if (lid == 255) bsum[blockIdx.x] = tmp[255];
}

__global__ void k_scan_bsum(const int* __restrict__ bsum, int* __restrict__ bexc, int nb) {
  __shared__ int tmp[512];
  int lid = threadIdx.x;
  int v = (lid < nb) ? bsum[lid] : 0;
  tmp[lid] = v;
  __syncthreads();
  for (int off = 1; off < 512; off <<= 1) {
    int t = (lid >= off) ? tmp[lid - off] : 0;
    __syncthreads();
    tmp[lid] += t;
    __syncthreads();
  }
  if (lid < nb) bexc[lid] = tmp[lid] - v;      // exclusive
}

__global__ void k_add_back(int* __restrict__ offs, const int* __restrict__ bexc,
                           const int* __restrict__ bsum, int N, int nb) {
  int i = blockIdx.x * 256 + threadIdx.x;
  if (i < N) offs[i] += bexc[blockIdx.x];
  if (i == 0) offs[N] = bexc[nb - 1] + bsum[nb - 1];   // total padded count
}

// slot = offs[dst] + rank  (no atomic; scatter store is fire-and-forget)
__global__ void k_fill_rank(const int* __restrict__ src, const int* __restrict__ dst,
                            const int* __restrict__ rank, const int* __restrict__ offs,
                            int* __restrict__ csr, int E) {
  int i = blockIdx.x * blockDim.x + threadIdx.x;
  int i4 = i << 2;
  if (i4 + 3 < E) {
    int s0 = src[i4], s1 = src[i4 + 1], s2 = src[i4 + 2], s3 = src[i4 + 3];
    int d0 = dst[i4], d1 = dst[i4 + 1], d2 = dst[i4 + 2], d3 = dst[i4 + 3];
    int r0 = rank[i4], r1 = rank[i4 + 1], r2 = rank[i4 + 2], r3 = rank[i4 + 3];
    csr[offs[d0] + r0] = s0;
    csr[offs[d1] + r1] = s1;
    csr[offs[d2] + r2] = s2;
    csr[offs[d3] + r3] = s3;
  } else {
    for (int e = i4; e < E; ++e) csr[offs[dst[e]] + rank[e]] = src[e];
  }
}

// fill dummy slots [offs+deg, offs+pdeg) with node N (zero row)
__global__ void k_pad_fill(const int* __restrict__ deg, const int* __restrict__ offs,
                           int* __restrict__ csr, int N) {
  int n = blockIdx.x * blockDim.x + threadIdx.x;
  if (n >= N) return;
  int b = offs[n] + deg[n], e = offs[n + 1];
  for (int j = b; j < e; ++j) csr[j] = N;
}

// ---------------- W prep: split-transpose to bf16 hi/lo + BN scale fold ----------------
__global__ void k_prep_w(const float* __restrict__ W2, const float* __restrict__ W3,
                         const float* __restrict__ b2, const float* __restrict__ g2,
                         const float* __restrict__ be2, const float* __restrict__ m2,
                         const float* __restrict__ v2,
                         const float* __restrict__ b3, const float* __restrict__ g3,
                         const float* __restrict__ be3, const float* __restrict__ m3,
                         const float* __restrict__ v3,
                         u16* __restrict__ Wht2, u16* __restrict__ Wlt2,
                         u16* __restrict__ Wht3, u16* __restrict__ Wlt3,
                         float* __restrict__ sc2, float* __restrict__ tc2,
                         float* __restrict__ sc3, float* __restrict__ tc3) {
  int idx = blockIdx.x * 256 + threadIdx.x;     // 0..32767
  int layer = idx >> 14;
  int e = idx & 16383;
  int c = e >> 7, k = e & 127;
  const float* W = layer ? W3 : W2;
  float w = W[k * 128 + c];                     // transpose read
  u32 h = f2bf(w);
  float l = w - __uint_as_float(h << 16);
  u16* Wh = layer ? Wht3 : Wht2;
  u16* Wl = layer ? Wlt3 : Wlt2;
  Wh[e] = (u16)h;                               // [c][k] layout
  Wl[e] = (u16)f2bf(l);
  if (e < 128) {
    int ch = e;
    const float* gg = layer ? g3 : g2;  const float* vv = layer ? v3 : v2;
    const float* be = layer ? be3 : be2; const float* mm = layer ? m3 : m2;
    const float* bb = layer ? b3 : b2;
    float s = gg[ch] * rsqrtf(vv[ch] + EPS);
    (layer ? sc3 : sc2)[ch] = s;
    (layer ? tc3 : tc2)[ch] = be[ch] + (bb[ch] - mm[ch]) * s;
  }
}

// ---------------- layer 1 ----------------
// xs = dis[n] * x (padded 13->16); row N zeroed
__global__ void k_padx_scale(const float* __restrict__ x, const float* __restrict__ dis,
                             float* __restrict__ xs, int N) {
  int i = blockIdx.x * blockDim.x + threadIdx.x;
  if (i >= (N + 1) * 16) return;
  int n = i >> 4, f = i & 15;
  xs[i] = (n < N && f < 13) ? x[n * 13 + f] * dis[n] : 0.0f;
}

// agg[d] = dis[d] * (sum_{s in padded N(d)} xs[s] + xs[d]); exact 4-edge steps
__global__ __launch_bounds__(64) void k_agg16(
    const float* __restrict__ xs, const int* __restrict__ csr,
    const int* __restrict__ offs, const float* __restrict__ dis,
    float* __restrict__ out, int N) {
  int node = (blockIdx.x << 2) + (threadIdx.x >> 4);
  if (node >= N) return;
  int f = threadIdx.x & 15;
  float a0 = xs[(size_t)node * 16 + f];   // self, weight 1
  float a1 = 0.f, a2 = 0.f, a3 = 0.f;
  int beg = offs[node], end = offs[node + 1];
  for (int i = beg; i < end; i += 4) {
    int4 s4 = *(const int4*)(csr + i);
    a0 += xs[(size_t)s4.x * 16 + f];
    a1 += xs[(size_t)s4.y * 16 + f];
    a2 += xs[(size_t)s4.z * 16 + f];
    a3 += xs[(size_t)s4.w * 16 + f];
  }
  out[(size_t)node * 16 + f] = dis[node] * ((a0 + a1) + (a2 + a3));
}

// K=13 GEMM + BN/ReLU, hs1 = dis*h1 bf16. Wave owns 128 channels (2/lane),
// W1 column + BN scale/shift in registers, grid-stride over nodes.
__global__ __launch_bounds__(256) void k_gemm1(
    const float* __restrict__ ax, const float* __restrict__ W1,
    const float* __restrict__ bb, const float* __restrict__ gg,
    const float* __restrict__ be, const float* __restrict__ mm,
    const float* __restrict__ vv, const float* __restrict__ dis,
    u32* __restrict__ outb, int N) {
  const int lane = threadIdx.x & 63;
  const int wid = blockIdx.x * (blockDim.x >> 6) + (threadIdx.x >> 6);
  const int nw = gridDim.x * (blockDim.x >> 6);
  const int c0 = lane * 2, c1 = c0 + 1;
  float s0 = gg[c0] * rsqrtf(vv[c0] + EPS);
  float t0 = be[c0] + (bb[c0] - mm[c0]) * s0;
  float s1 = gg[c1] * rsqrtf(vv[c1] + EPS);
  float t1 = be[c1] + (bb[c1] - mm[c1]) * s1;
  float w0[13], w1[13];
#pragma unroll
  for (int k = 0; k < 13; ++k) {
    w0[k] = W1[k * 128 + c0];
    w1[k] = W1[k * 128 + c1];
  }
  for (int node = wid; node <= N; node += nw) {
    if (node == N) { outb[(size_t)node * 64 + lane] = 0u; continue; }
    // wave-uniform row read (one cache line, broadcast)
    float4 A0 = *(const float4*)(ax + (size_t)node * 16);
    float4 A1 = *(const float4*)(ax + (size_t)node * 16 + 4);
    float4 A2 = *(const float4*)(ax + (size_t)node * 16 + 8);
    float  a12 = ax[(size_t)node * 16 + 12];
    float av[13] = {A0.x, A0.y, A0.z, A0.w, A1.x, A1.y, A1.z, A1.w,
                    A2.x, A2.y, A2.z, A2.w, a12};
    float acc0 = 0.f, acc1 = 0.f;
#pragma unroll
    for (int k = 0; k < 13; ++k) {
      acc0 = fmaf(av[k], w0[k], acc0);
      acc1 = fmaf(av[k], w1[k], acc1);
    }
    float dn = dis[node];
    float o0 = dn * fmaxf(fmaf(acc0, s0, t0), 0.f);
    float o1 = dn * fmaxf(fmaf(acc1, s1, t1), 0.f);
    outb[(size_t)node * 64 + lane] = pack2bf(o0, o1);
  }
}

// ---- 128-feat aggregation, quad scheme: 1 wave/node, 4 edges/step, uint4/lane ----
// out = dis[d]*(sum hs[s] + hs[d]) -> split bf16 planes Ah (hi) / Al (residual)
__global__ __launch_bounds__(256) void k_agg128(
    const u16* __restrict__ hb, const int* __restrict__ csr,
    const int* __restrict__ offs, const float* __restrict__ dis,
    uint4* __restrict__ Ahp, uint4* __restrict__ Alp, int N) {
  int node = (blockIdx.x << 2) + (threadIdx.x >> 6);
  if (node >= N) return;
  node = __builtin_amdgcn_readfirstlane(node);   // wave-uniform by construction
  const int lane = threadIdx.x & 63;
  const int qt = lane >> 4;      // edge slot within quad (0..3)
  const int q = lane & 15;       // uint4 slot = features 8q..8q+7
  const uint4* __restrict__ H = (const uint4*)hb;
  int beg = offs[node], end = offs[node + 1];    // multiple-of-4 segment

  float2 z2 = make_float2(0.f, 0.f);
  float2 aA0 = z2, aA1 = z2, aA2 = z2, aA3 = z2;
  float2 aB0 = z2, aB1 = z2, aB2 = z2, aB3 = z2;

  // self term (weight 1), qt==0 lanes only
  {
    uint4 su = H[(size_t)node * 16 + q];
    if (qt == 0) { dacc(aA0, su.x); dacc(aA1, su.y); dacc(aA2, su.z); dacc(aA3, su.w); }
  }

  int i = beg;
  for (; i + 8 <= end; i += 8) {     // 8 edges, 2 independent quad-streams
    int4 sA = *(const int4*)(csr + i);
    int4 sB = *(const int4*)(csr + i + 4);
    int ea = (qt == 0) ? sA.x : (qt == 1) ? sA.y : (qt == 2) ? sA.z : sA.w;
    int eb = (qt == 0) ? sB.x : (qt == 1) ? sB.y : (qt == 2) ? sB.z : sB.w;
    uint4 uA = H[(size_t)ea * 16 + q];
    uint4 uB = H[(size_t)eb * 16 + q];
    dacc(aA0, uA.x); dacc(aA1, uA.y); dacc(aA2, uA.z); dacc(aA3, uA.w);
    dacc(aB0, uB.x); dacc(aB1, uB.y); dacc(aB2, uB.z); dacc(aB3, uB.w);
  }
  if (i < end) {                     // exactly one remaining quad
    int4 sA = *(const int4*)(csr + i);
    int ea = (qt == 0) ? sA.x : (qt == 1) ? sA.y : (qt == 2) ? sA.z : sA.w;
    uint4 uA = H[(size_t)ea * 16 + q];
    dacc(aA0, uA.x); dacc(aA1, uA.y); dacc(aA2, uA.z); dacc(aA3, uA.w);
  }

  float r[8];
  r[0] = aA0.x + aB0.x; r[1] = aA0.y + aB0.y;
  r[2] = aA1.x + aB1.x; r[3] = aA1.y + aB1.y;
  r[4] = aA2.x + aB2.x; r[5] = aA2.y + aB2.y;
  r[6] = aA3.x + aB3.x; r[7] = aA3.y + aB3.y;
#pragma unroll
  for (int j = 0; j < 8; ++j) {
    r[j] += __shfl_xor(r[j], 16, 64);
    r[j] += __shfl_xor(r[j], 32, 64);
  }
  if (qt == 0) {
    float dn = dis[node];
    uint4 ph, pl;
    u32 hw[8];
#pragma unroll
    for (int j = 0; j < 8; ++j) { r[j] *= dn; hw[j] = f2bf(r[j]); }
    ph.x = hw[0] | (hw[1] << 16);
    ph.y = hw[2] | (hw[3] << 16);
    ph.z = hw[4] | (hw[5] << 16);
    ph.w = hw[6] | (hw[7] << 16);
    float l[8];
#pragma unroll
    for (int j = 0; j < 8; ++j) l[j] = r[j] - __uint_as_float(hw[j] << 16);
    pl.x = pack2bf(l[0], l[1]);
    pl.y = pack2bf(l[2], l[3]);
    pl.z = pack2bf(l[4], l[5]);
    pl.w = pack2bf(l[6], l[7]);
    Ahp[(size_t)node * 16 + q] = ph;
    Alp[(size_t)node * 16 + q] = pl;
  }
}

// ---- H x H GEMM via bf16x3-split MFMA (16x16x32), no LDS, 32 rows/wave ----
template <bool OB>
__global__ __launch_bounds__(256) void k_gemm_mfma(
    const u16* __restrict__ Ah, const u16* __restrict__ Al,
    const u16* __restrict__ Wht, const u16* __restrict__ Wlt,
    const float* __restrict__ sc, const float* __restrict__ tc,
    const float* __restrict__ dis,
    float* __restrict__ outf, u16* __restrict__ outb, int N) {
  const int lane = threadIdx.x & 63;
  const int wv = threadIdx.x >> 6;            // wave 0..3
  const int r0 = blockIdx.x * 128 + wv * 32;  // this wave: rows r0..r0+31
  const int lr = lane & 15;
  const int kg = lane >> 4;                   // k-group 0..3

  bf16x8 ahf[2][4], alf[2][4];
#pragma unroll
  for (int rt = 0; rt < 2; ++rt) {
    int row = min(r0 + rt * 16 + lr, N - 1);
    const bf16x8* pAh = (const bf16x8*)(Ah + (size_t)row * 128 + kg * 8);
    const bf16x8* pAl = (const bf16x8*)(Al + (size_t)row * 128 + kg * 8);
#pragma unroll
    for (int ks = 0; ks < 4; ++ks) {
      ahf[rt][ks] = pAh[ks * 4];
      alf[rt][ks] = pAl[ks * 4];
    }
  }
  float dr[2][4];
  if (OB) {
#pragma unroll
    for (int rt = 0; rt < 2; ++rt)
#pragma unroll
      for (int j = 0; j < 4; ++j)
        dr[rt][j] = dis[min(r0 + rt * 16 + kg * 4 + j, N - 1)];
  }

#pragma unroll
  for (int ct = 0; ct < 8; ++ct) {
    int c = ct * 16 + lr;
    const bf16x8* pBh = (const bf16x8*)(Wht + (size_t)c * 128 + kg * 8);
    const bf16x8* pBl = (const bf16x8*)(Wlt + (size_t)c * 128 + kg * 8);
    bf16x8 bh[4], bl[4];
#pragma unroll
    for (int ks = 0; ks < 4; ++ks) { bh[ks] = pBh[ks * 4]; bl[ks] = pBl[ks * 4]; }
    float s = sc[c], t = tc[c];
#pragma unroll
    for (int rt = 0; rt < 2; ++rt) {
      f32x4 acc = {0.f, 0.f, 0.f, 0.f};
#pragma unroll
      for (int ks = 0; ks < 4; ++ks) {
        acc = __builtin_amdgcn_mfma_f32_16x16x32_bf16(ahf[rt][ks], bh[ks], acc, 0, 0, 0);
        acc = __builtin_amdgcn_mfma_f32_16x16x32_bf16(alf[rt][ks], bh[ks], acc, 0, 0, 0);
        acc = __builtin_amdgcn_mfma_f32_16x16x32_bf16(ahf[rt][ks], bl[ks], acc, 0, 0, 0);
      }
      // C/D: col = lane&15, row = (lane>>4)*4 + j   [m89-verified]
#pragma unroll
      for (int j = 0; j < 4; ++j) {
        int row = r0 + rt * 16 + kg * 4 + j;
        if (row < N) {
          float o = fmaxf(fmaf(acc[j], s, t), 0.f);
          if (OB) {
            outb[(size_t)row * 128 + c] = (u16)f2bf(o * dr[rt][j]);
          } else {
            outf[(size_t)row * 128 + c] = o;
          }
        }
      }
    }
  }
}

// ---------------- pooling + classifier ----------------
__global__ void k_cnt_batch(const int* __restrict__ batch, int* __restrict__ cnt,
                            int N, int G) {
  int g = blockIdx.x * blockDim.x + threadIdx.x;
  if (g >= G) return;
  int lo = 0, hi = N;
  while (lo < hi) { int m = (lo + hi) >> 1; if (batch[m] < g) lo = m + 1; else hi = m; }
  int lb = lo;
  lo = 0; hi = N;
  while (lo < hi) { int m = (lo + hi) >> 1; if (batch[m] <= g) lo = m + 1; else hi = m; }
  cnt[g] = lo - lb;
}

__global__ __launch_bounds__(128) void k_pool(
    const float* __restrict__ h, const int* __restrict__ batch,
    float* __restrict__ pooled, int N) {
  int f = threadIdx.x;
  int n0 = blockIdx.x * 128;
  int nEnd = min(n0 + 128, N);
  float acc = 0.f;
  int cur = -1;
  for (int nn = n0; nn < nEnd; ++nn) {
    int g = batch[nn];
    if (g != cur) {
      if (cur >= 0) atomicAdd(&pooled[cur * 128 + f], acc);
      cur = g;
      acc = 0.f;
    }
    acc += h[(size_t)nn * 128 + f];
  }
  if (cur >= 0) atomicAdd(&pooled[cur * 128 + f], acc);
}

__global__ __launch_bounds__(64) void k_cls(
    const float* __restrict__ pooled, const int* __restrict__ cnt,
    const float* __restrict__ Wc1, const float* __restrict__ bc1,
    const float* __restrict__ Wc2, const float* __restrict__ bc2,
    float* __restrict__ out, int G) {
  __shared__ float pm[128];
  __shared__ float hid[64];
  int g = blockIdx.x, t = threadIdx.x;
  float invc = 1.f / fmaxf((float)cnt[g], 1.f);
  pm[t]      = pooled[g * 128 + t] * invc;
  pm[t + 64] = pooled[g * 128 + 64 + t] * invc;
  __syncthreads();
  float a = bc1[t];
#pragma unroll 8
  for (int k = 0; k < 128; ++k) a = fmaf(pm[k], Wc1[k * 64 + t], a);
  hid[t] = fmaxf(a, 0.f);
  __syncthreads();
  if (t < 10) {
    float a2 = bc2[t];
#pragma unroll
    for (int j = 0; j < 64; ++j) a2 = fmaf(hid[j], Wc2[j * 10 + t], a2);
    out[g * 10 + t] = a2;
  }
}

extern "C" void kernel_launch(void* const* d_in, const int* in_sizes, int n_in,
                              void* d_out, int out_size, void* d_ws, size_t ws_size,
                              hipStream_t stream) {
  const float* x   = (const float*)d_in[0];
  const int*   ei  = (const int*)d_in[1];
  const int* batch = (const int*)d_in[2];
  const float* W1 = (const float*)d_in[3];
  const float* b1 = (const float*)d_in[4];
  const float* g1 = (const float*)d_in[5];
  const float* be1 = (const float*)d_in[6];
  const float* m1 = (const float*)d_in[7];
  const float* v1 = (const float*)d_in[8];
  const float* W2 = (const float*)d_in[9];
  const float* b2 = (const float*)d_in[10];
  const float* g2 = (const float*)d_in[11];
  const float* be2 = (const float*)d_in[12];
  const float* m2 = (const float*)d_in[13];
  const float* v2 = (const float*)d_in[14];
  const float* W3 = (const float*)d_in[15];
  const float* b3 = (const float*)d_in[16];
  const float* g3 = (const float*)d_in[17];
  const float* be3 = (const float*)d_in[18];
  const float* m3 = (const float*)d_in[19];
  const float* v3 = (const float*)d_in[20];
  const float* Wc1 = (const float*)d_in[21];
  const float* bc1 = (const float*)d_in[22];
  const float* Wc2 = (const float*)d_in[23];
  const float* bc2 = (const float*)d_in[24];

  const int N = in_sizes[0] / 13;
  const int E = in_sizes[1] / 2;
  const int G = out_size / 10;
  const int* src = ei;
  const int* dst = ei + E;

  char* ws = (char*)d_ws;
  size_t off = 0;
  auto alloc = [&](size_t bytes) {
    char* p = ws + off;
    off = (off + bytes + 255) & ~(size_t)255;
    return p;
  };
  int*   deg    = (int*)  alloc((size_t)N * 4);
  float* dis    = (float*)alloc((size_t)N * 4);
  int*   pdeg   = (int*)  alloc((size_t)N * 4);
  int*   offs   = (int*)  alloc((size_t)(N + 1) * 4);
  const int nb  = (N + 255) / 256;
  int*   bsum   = (int*)  alloc((size_t)nb * 4);
  int*   bexc   = (int*)  alloc((size_t)nb * 4);
  int*   rank   = (int*)  alloc((size_t)E * 4);
  int*   csr    = (int*)  alloc(((size_t)E + 3 * (size_t)N + 8) * 4);
  u16*   hbf    = (u16*)  alloc((size_t)(N + 1) * 128 * 2);   // hs bf16, row N = 0
  u16*   Ahp    = (u16*)  alloc((size_t)N * 128 * 2);         // agg out hi
  u16*   Alp    = (u16*)  alloc((size_t)N * 128 * 2);         // agg out lo residual
  float* bufF   = (float*)alloc((size_t)(N + 1) * 128 * 4);   // xs first, then fp32 h3
  u16*   Wht2   = (u16*)  alloc(16384 * 2);
  u16*   Wlt2   = (u16*)  alloc(16384 * 2);
  u16*   Wht3   = (u16*)  alloc(16384 * 2);
  u16*   Wlt3   = (u16*)  alloc(16384 * 2);
  float* sc2    = (float*)alloc(128 * 4);
  float* tc2    = (float*)alloc(128 * 4);
  float* sc3    = (float*)alloc(128 * 4);
  float* tc3    = (float*)alloc(128 * 4);
  float* pooled = (float*)alloc((size_t)G * 128 * 4);
  int*   cntg   = (int*)  alloc((size_t)G * 4);
  float* xs = bufF;          // [(N+1),16] alias (dead before bufF reused for h3)
  float* ax = (float*)Ahp;   // [N,16] alias (consumed before agg128 writes Ahp)

  hipMemsetAsync(deg, 0, (size_t)N * 4, stream);
  hipMemsetAsync(pooled, 0, (size_t)G * 128 * 4, stream);

  k_prep_w<<<128, 256, 0, stream>>>(W2, W3, b2, g2, be2, m2, v2, b3, g3, be3, m3, v3,
                                    Wht2, Wlt2, Wht3, Wlt3, sc2, tc2, sc3, tc3);

  const int nE4 = (E + 3) / 4;
  k_hist_rank<<<(nE4 + 255) / 256, 256, 0, stream>>>(dst, deg, rank, E);
  k_dis_pdeg<<<(N + 255) / 256, 256, 0, stream>>>(deg, dis, pdeg, N);
  k_scan_block<<<nb, 256, 0, stream>>>(pdeg, offs, bsum, N);
  k_scan_bsum<<<1, 512, 0, stream>>>(bsum, bexc, nb);
  k_add_back<<<nb, 256, 0, stream>>>(offs, bexc, bsum, N, nb);
  k_fill_rank<<<(nE4 + 255) / 256, 256, 0, stream>>>(src, dst, rank, offs, csr, E);
  k_pad_fill<<<(N + 255) / 256, 256, 0, stream>>>(deg, offs, csr, N);

  k_padx_scale<<<((N + 1) * 16 + 255) / 256, 256, 0, stream>>>(x, dis, xs, N);
  k_agg16<<<(N + 3) / 4, 64, 0, stream>>>(xs, csr, offs, dis, ax, N);
  k_gemm1<<<1024, 256, 0, stream>>>(ax, W1, b1, g1, be1, m1, v1, dis, (u32*)hbf, N);

  const int gemmGrid = (N + 127) / 128;
  k_agg128<<<(N + 3) / 4, 256, 0, stream>>>(hbf, csr, offs, dis,
                                            (uint4*)Ahp, (uint4*)Alp, N);
  k_gemm_mfma<true><<<gemmGrid, 256, 0, stream>>>(Ahp, Alp, Wht2, Wlt2, sc2, tc2, dis,
                                                  nullptr, hbf, N);
  k_agg128<<<(N + 3) / 4, 256, 0, stream>>>(hbf, csr, offs, dis,
                                            (uint4*)Ahp, (uint4*)Alp, N);
  k_gemm_mfma<false><<<gemmGrid, 256, 0, stream>>>(Ahp, Alp, Wht3, Wlt3, sc3, tc3, dis,
                                                   bufF, nullptr, N);

  k_cnt_batch<<<(G + 255) / 256, 256, 0, stream>>>(batch, cntg, N, G);
  k_pool<<<(N + 127) / 128, 128, 0, stream>>>(bufF, batch, pooled, N);
  k_cls<<<G, 64, 0, stream>>>(pooled, cntg, Wc1, bc1, Wc2, bc2, (float*)d_out, G);
}

// Round 10
// 532.608 us; speedup vs baseline: 2.2538x; 1.0145x over previous
//
#include <hip/hip_runtime.h>
#include <hip/hip_bf16.h>

#define EPS 1e-5f

typedef unsigned short u16;
typedef unsigned int u32;
typedef __attribute__((ext_vector_type(8))) short bf16x8;
typedef __attribute__((ext_vector_type(4))) float f32x4;

// ---- bf16 helpers (RNE encode, shift decode) ----
__device__ __forceinline__ u32 f2bf(float f) {
  u32 u = __float_as_uint(f);
  return (u + 0x7FFFu + ((u >> 16) & 1u)) >> 16;
}
__device__ __forceinline__ u32 pack2bf(float lo, float hi) {
  return f2bf(lo) | (f2bf(hi) << 16);
}

// accumulate 2 packed bf16 into float2 accumulator
__device__ __forceinline__ void dacc(float2& a, u32 u) {
  a.x += __uint_as_float(u << 16);
  a.y += __uint_as_float(u & 0xFFFF0000u);
}

// ---------------- CSR build: histogram + per-edge rank (8 edges/thread) ----------------
__global__ void k_hist_rank(const int* __restrict__ dst, int* __restrict__ cnt,
                            int* __restrict__ rank, int E) {
  int i = blockIdx.x * blockDim.x + threadIdx.x;
  int i8 = i << 3;
  if (i8 + 7 < E) {
    int4 da = *(const int4*)(dst + i8);
    int4 db = *(const int4*)(dst + i8 + 4);
    int r0 = atomicAdd(&cnt[da.x], 1);
    int r1 = atomicAdd(&cnt[da.y], 1);
    int r2 = atomicAdd(&cnt[da.z], 1);
    int r3 = atomicAdd(&cnt[da.w], 1);
    int r4 = atomicAdd(&cnt[db.x], 1);
    int r5 = atomicAdd(&cnt[db.y], 1);
    int r6 = atomicAdd(&cnt[db.z], 1);
    int r7 = atomicAdd(&cnt[db.w], 1);
    *(int4*)(rank + i8)     = make_int4(r0, r1, r2, r3);
    *(int4*)(rank + i8 + 4) = make_int4(r4, r5, r6, r7);
  } else {
    for (int e = i8; e < E; ++e) rank[e] = atomicAdd(&cnt[dst[e]], 1);
  }
}

// fused: dis, pdeg, and xs = dis * x (padded 13->16, row N zeroed)
__global__ void k_prep_nodes(const int* __restrict__ cnt, const float* __restrict__ x,
                             float* __restrict__ dis, int* __restrict__ pdeg,
                             float* __restrict__ xs, int N) {
  int n = blockIdx.x * blockDim.x + threadIdx.x;
  if (n > N) return;
  if (n == N) {
#pragma unroll
    for (int f = 0; f < 16; f += 4)
      *(float4*)(xs + (size_t)N * 16 + f) = make_float4(0.f, 0.f, 0.f, 0.f);
    return;
  }
  int d = cnt[n];
  float dn = rsqrtf((float)d + 1.0f);
  dis[n] = dn;
  pdeg[n] = (d + 3) & ~3;
  float v[16];
#pragma unroll
  for (int f = 0; f < 13; ++f) v[f] = x[(size_t)n * 13 + f] * dn;
  v[13] = v[14] = v[15] = 0.f;
#pragma unroll
  for (int f = 0; f < 16; f += 4)
    *(float4*)(xs + (size_t)n * 16 + f) = make_float4(v[f], v[f+1], v[f+2], v[f+3]);
}

__global__ void k_scan_block(const int* __restrict__ in, int* __restrict__ out,
                             int* __restrict__ bsum, int N) {
  __shared__ int tmp[256];
  int lid = threadIdx.x;
  int i = blockIdx.x * 256 + lid;
  int v = (i < N) ? in[i] : 0;
  tmp[lid] = v;
  __syncthreads();
  for (int off = 1; off < 256; off <<= 1) {
    int t = (lid >= off) ? tmp[lid - off] : 0;
    __syncthreads();
    tmp[lid] += t;
    __syncthreads();
  }
  if (i < N) out[i] = tmp[lid] - v;            // exclusive within block
  if (lid == 255) bsum[blockIdx.x] = tmp[255];
}

__global__ void k_scan_bsum(const int* __restrict__ bsum, int* __restrict__ bexc, int nb) {
  __shared__ int tmp[512];
  int lid = threadIdx.x;
  int v = (lid < nb) ? bsum[lid] : 0;
  tmp[lid] = v;
  __syncthreads();
  for (int off = 1; off < 512; off <<= 1) {
    int t = (lid >= off) ? tmp[lid - off] : 0;
    __syncthreads();
    tmp[lid] += t;
    __syncthreads();
  }
  if (lid < nb) bexc[lid] = tmp[lid] - v;      // exclusive
}

// fused: finalize offs + fill dummy pad slots (disjoint from real slots, order-free)
__global__ void k_add_back_pad(int* __restrict__ offs, const int* __restrict__ bexc,
                               const int* __restrict__ bsum, const int* __restrict__ deg,
                               const int* __restrict__ pdeg, int* __restrict__ csr,
                               int N, int nb) {
  int i = blockIdx.x * 256 + threadIdx.x;
  if (i < N) {
    int o = offs[i] + bexc[blockIdx.x];
    offs[i] = o;
    int b = o + deg[i], e = o + pdeg[i];
    for (int j = b; j < e; ++j) csr[j] = N;
  }
  if (i == 0) offs[N] = bexc[nb - 1] + bsum[nb - 1];   // total padded count
}

// slot = offs[dst] + rank  (no atomic; scatter store is fire-and-forget)
__global__ void k_fill_rank(const int* __restrict__ src, const int* __restrict__ dst,
                            const int* __restrict__ rank, const int* __restrict__ offs,
                            int* __restrict__ csr, int E) {
  int i = blockIdx.x * blockDim.x + threadIdx.x;
  int i4 = i << 2;
  if (i4 + 3 < E) {
    int s0 = src[i4], s1 = src[i4 + 1], s2 = src[i4 + 2], s3 = src[i4 + 3];
    int d0 = dst[i4], d1 = dst[i4 + 1], d2 = dst[i4 + 2], d3 = dst[i4 + 3];
    int r0 = rank[i4], r1 = rank[i4 + 1], r2 = rank[i4 + 2], r3 = rank[i4 + 3];
    csr[offs[d0] + r0] = s0;
    csr[offs[d1] + r1] = s1;
    csr[offs[d2] + r2] = s2;
    csr[offs[d3] + r3] = s3;
  } else {
    for (int e = i4; e < E; ++e) csr[offs[dst[e]] + rank[e]] = src[e];
  }
}

// ---------------- W prep: split-transpose to bf16 hi/lo + BN scale fold ----------------
__global__ void k_prep_w(const float* __restrict__ W2, const float* __restrict__ W3,
                         const float* __restrict__ b2, const float* __restrict__ g2,
                         const float* __restrict__ be2, const float* __restrict__ m2,
                         const float* __restrict__ v2,
                         const float* __restrict__ b3, const float* __restrict__ g3,
                         const float* __restrict__ be3, const float* __restrict__ m3,
                         const float* __restrict__ v3,
                         u16* __restrict__ Wht2, u16* __restrict__ Wlt2,
                         u16* __restrict__ Wht3, u16* __restrict__ Wlt3,
                         float* __restrict__ sc2, float* __restrict__ tc2,
                         float* __restrict__ sc3, float* __restrict__ tc3) {
  int idx = blockIdx.x * 256 + threadIdx.x;     // 0..32767
  int layer = idx >> 14;
  int e = idx & 16383;
  int c = e >> 7, k = e & 127;
  const float* W = layer ? W3 : W2;
  float w = W[k * 128 + c];                     // transpose read
  u32 h = f2bf(w);
  float l = w - __uint_as_float(h << 16);
  u16* Wh = layer ? Wht3 : Wht2;
  u16* Wl = layer ? Wlt3 : Wlt2;
  Wh[e] = (u16)h;                               // [c][k] layout
  Wl[e] = (u16)f2bf(l);
  if (e < 128) {
    int ch = e;
    const float* gg = layer ? g3 : g2;  const float* vv = layer ? v3 : v2;
    const float* be = layer ? be3 : be2; const float* mm = layer ? m3 : m2;
    const float* bb = layer ? b3 : b2;
    float s = gg[ch] * rsqrtf(vv[ch] + EPS);
    (layer ? sc3 : sc2)[ch] = s;
    (layer ? tc3 : tc2)[ch] = be[ch] + (bb[ch] - mm[ch]) * s;
  }
}

// agg[d] = dis[d] * (sum_{s in padded N(d)} xs[s] + xs[d]); exact 4-edge steps
__global__ __launch_bounds__(64) void k_agg16(
    const float* __restrict__ xs, const int* __restrict__ csr,
    const int* __restrict__ offs, const float* __restrict__ dis,
    float* __restrict__ out, int N) {
  int node = (blockIdx.x << 2) + (threadIdx.x >> 4);
  if (node >= N) return;
  int f = threadIdx.x & 15;
  float a0 = xs[(size_t)node * 16 + f];   // self, weight 1
  float a1 = 0.f, a2 = 0.f, a3 = 0.f;
  int beg = offs[node], end = offs[node + 1];
  for (int i = beg; i < end; i += 4) {
    int4 s4 = *(const int4*)(csr + i);
    a0 += xs[(size_t)s4.x * 16 + f];
    a1 += xs[(size_t)s4.y * 16 + f];
    a2 += xs[(size_t)s4.z * 16 + f];
    a3 += xs[(size_t)s4.w * 16 + f];
  }
  out[(size_t)node * 16 + f] = dis[node] * ((a0 + a1) + (a2 + a3));
}

// K=13 GEMM + BN/ReLU, hs1 = dis*h1 bf16. Wave owns 128 channels (2/lane),
// W1 column + BN scale/shift in registers, grid-stride over nodes.
__global__ __launch_bounds__(256) void k_gemm1(
    const float* __restrict__ ax, const float* __restrict__ W1,
    const float* __restrict__ bb, const float* __restrict__ gg,
    const float* __restrict__ be, const float* __restrict__ mm,
    const float* __restrict__ vv, const float* __restrict__ dis,
    u32* __restrict__ outb, int N) {
  const int lane = threadIdx.x & 63;
  const int wid = blockIdx.x * (blockDim.x >> 6) + (threadIdx.x >> 6);
  const int nw = gridDim.x * (blockDim.x >> 6);
  const int c0 = lane * 2, c1 = c0 + 1;
  float s0 = gg[c0] * rsqrtf(vv[c0] + EPS);
  float t0 = be[c0] + (bb[c0] - mm[c0]) * s0;
  float s1 = gg[c1] * rsqrtf(vv[c1] + EPS);
  float t1 = be[c1] + (bb[c1] - mm[c1]) * s1;
  float w0[13], w1[13];
#pragma unroll
  for (int k = 0; k < 13; ++k) {
    w0[k] = W1[k * 128 + c0];
    w1[k] = W1[k * 128 + c1];
  }
  for (int node = wid; node <= N; node += nw) {
    if (node == N) { outb[(size_t)node * 64 + lane] = 0u; continue; }
    float4 A0 = *(const float4*)(ax + (size_t)node * 16);
    float4 A1 = *(const float4*)(ax + (size_t)node * 16 + 4);
    float4 A2 = *(const float4*)(ax + (size_t)node * 16 + 8);
    float  a12 = ax[(size_t)node * 16 + 12];
    float av[13] = {A0.x, A0.y, A0.z, A0.w, A1.x, A1.y, A1.z, A1.w,
                    A2.x, A2.y, A2.z, A2.w, a12};
    float acc0 = 0.f, acc1 = 0.f;
#pragma unroll
    for (int k = 0; k < 13; ++k) {
      acc0 = fmaf(av[k], w0[k], acc0);
      acc1 = fmaf(av[k], w1[k], acc1);
    }
    float dn = dis[node];
    float o0 = dn * fmaxf(fmaf(acc0, s0, t0), 0.f);
    float o1 = dn * fmaxf(fmaf(acc1, s1, t1), 0.f);
    outb[(size_t)node * 64 + lane] = pack2bf(o0, o1);
  }
}

// ---- 128-feat aggregation, quad scheme: 1 wave/node, 4 edges/step, uint4/lane ----
__global__ __launch_bounds__(256) void k_agg128(
    const u16* __restrict__ hb, const int* __restrict__ csr,
    const int* __restrict__ offs, const float* __restrict__ dis,
    uint4* __restrict__ Ahp, uint4* __restrict__ Alp, int N) {
  int node = (blockIdx.x << 2) + (threadIdx.x >> 6);
  if (node >= N) return;
  node = __builtin_amdgcn_readfirstlane(node);   // wave-uniform by construction
  const int lane = threadIdx.x & 63;
  const int qt = lane >> 4;      // edge slot within quad (0..3)
  const int q = lane & 15;       // uint4 slot = features 8q..8q+7
  const uint4* __restrict__ H = (const uint4*)hb;
  int beg = offs[node], end = offs[node + 1];    // multiple-of-4 segment

  float2 z2 = make_float2(0.f, 0.f);
  float2 aA0 = z2, aA1 = z2, aA2 = z2, aA3 = z2;
  float2 aB0 = z2, aB1 = z2, aB2 = z2, aB3 = z2;

  {
    uint4 su = H[(size_t)node * 16 + q];
    if (qt == 0) { dacc(aA0, su.x); dacc(aA1, su.y); dacc(aA2, su.z); dacc(aA3, su.w); }
  }

  int i = beg;
  for (; i + 8 <= end; i += 8) {
    int4 sA = *(const int4*)(csr + i);
    int4 sB = *(const int4*)(csr + i + 4);
    int ea = (qt == 0) ? sA.x : (qt == 1) ? sA.y : (qt == 2) ? sA.z : sA.w;
    int eb = (qt == 0) ? sB.x : (qt == 1) ? sB.y : (qt == 2) ? sB.z : sB.w;
    uint4 uA = H[(size_t)ea * 16 + q];
    uint4 uB = H[(size_t)eb * 16 + q];
    dacc(aA0, uA.x); dacc(aA1, uA.y); dacc(aA2, uA.z); dacc(aA3, uA.w);
    dacc(aB0, uB.x); dacc(aB1, uB.y); dacc(aB2, uB.z); dacc(aB3, uB.w);
  }
  if (i < end) {
    int4 sA = *(const int4*)(csr + i);
    int ea = (qt == 0) ? sA.x : (qt == 1) ? sA.y : (qt == 2) ? sA.z : sA.w;
    uint4 uA = H[(size_t)ea * 16 + q];
    dacc(aA0, uA.x); dacc(aA1, uA.y); dacc(aA2, uA.z); dacc(aA3, uA.w);
  }

  float r[8];
  r[0] = aA0.x + aB0.x; r[1] = aA0.y + aB0.y;
  r[2] = aA1.x + aB1.x; r[3] = aA1.y + aB1.y;
  r[4] = aA2.x + aB2.x; r[5] = aA2.y + aB2.y;
  r[6] = aA3.x + aB3.x; r[7] = aA3.y + aB3.y;
#pragma unroll
  for (int j = 0; j < 8; ++j) {
    r[j] += __shfl_xor(r[j], 16, 64);
    r[j] += __shfl_xor(r[j], 32, 64);
  }
  if (qt == 0) {
    float dn = dis[node];
    uint4 ph, pl;
    u32 hw[8];
#pragma unroll
    for (int j = 0; j < 8; ++j) { r[j] *= dn; hw[j] = f2bf(r[j]); }
    ph.x = hw[0] | (hw[1] << 16);
    ph.y = hw[2] | (hw[3] << 16);
    ph.z = hw[4] | (hw[5] << 16);
    ph.w = hw[6] | (hw[7] << 16);
    float l[8];
#pragma unroll
    for (int j = 0; j < 8; ++j) l[j] = r[j] - __uint_as_float(hw[j] << 16);
    pl.x = pack2bf(l[0], l[1]);
    pl.y = pack2bf(l[2], l[3]);
    pl.z = pack2bf(l[4], l[5]);
    pl.w = pack2bf(l[6], l[7]);
    Ahp[(size_t)node * 16 + q] = ph;
    Alp[(size_t)node * 16 + q] = pl;
  }
}

// ---- H x H GEMM via bf16x3-split MFMA (16x16x32), no LDS, 32 rows/wave ----
// MODE 0: out bf16 = dis*relu(...)  (hs for next layer)
// MODE 1: out bf16 = relu(...)      (h3, consumed by pooling)
template <int MODE>
__global__ __launch_bounds__(256) void k_gemm_mfma(
    const u16* __restrict__ Ah, const u16* __restrict__ Al,
    const u16* __restrict__ Wht, const u16* __restrict__ Wlt,
    const float* __restrict__ sc, const float* __restrict__ tc,
    const float* __restrict__ dis,
    u16* __restrict__ outb, int N) {
  const int lane = threadIdx.x & 63;
  const int wv = threadIdx.x >> 6;            // wave 0..3
  const int r0 = blockIdx.x * 128 + wv * 32;  // this wave: rows r0..r0+31
  const int lr = lane & 15;
  const int kg = lane >> 4;                   // k-group 0..3

  bf16x8 ahf[2][4], alf[2][4];
#pragma unroll
  for (int rt = 0; rt < 2; ++rt) {
    int row = min(r0 + rt * 16 + lr, N - 1);
    const bf16x8* pAh = (const bf16x8*)(Ah + (size_t)row * 128 + kg * 8);
    const bf16x8* pAl = (const bf16x8*)(Al + (size_t)row * 128 + kg * 8);
#pragma unroll
    for (int ks = 0; ks < 4; ++ks) {
      ahf[rt][ks] = pAh[ks * 4];
      alf[rt][ks] = pAl[ks * 4];
    }
  }
  float dr[2][4];
  if (MODE == 0) {
#pragma unroll
    for (int rt = 0; rt < 2; ++rt)
#pragma unroll
      for (int j = 0; j < 4; ++j)
        dr[rt][j] = dis[min(r0 + rt * 16 + kg * 4 + j, N - 1)];
  }

#pragma unroll
  for (int ct = 0; ct < 8; ++ct) {
    int c = ct * 16 + lr;
    const bf16x8* pBh = (const bf16x8*)(Wht + (size_t)c * 128 + kg * 8);
    const bf16x8* pBl = (const bf16x8*)(Wlt + (size_t)c * 128 + kg * 8);
    bf16x8 bh[4], bl[4];
#pragma unroll
    for (int ks = 0; ks < 4; ++ks) { bh[ks] = pBh[ks * 4]; bl[ks] = pBl[ks * 4]; }
    float s = sc[c], t = tc[c];
#pragma unroll
    for (int rt = 0; rt < 2; ++rt) {
      f32x4 acc = {0.f, 0.f, 0.f, 0.f};
#pragma unroll
      for (int ks = 0; ks < 4; ++ks) {
        acc = __builtin_amdgcn_mfma_f32_16x16x32_bf16(ahf[rt][ks], bh[ks], acc, 0, 0, 0);
        acc = __builtin_amdgcn_mfma_f32_16x16x32_bf16(alf[rt][ks], bh[ks], acc, 0, 0, 0);
        acc = __builtin_amdgcn_mfma_f32_16x16x32_bf16(ahf[rt][ks], bl[ks], acc, 0, 0, 0);
      }
      // C/D: col = lane&15, row = (lane>>4)*4 + j   [m89-verified]
#pragma unroll
      for (int j = 0; j < 4; ++j) {
        int row = r0 + rt * 16 + kg * 4 + j;
        if (row < N) {
          float o = fmaxf(fmaf(acc[j], s, t), 0.f);
          if (MODE == 0) o *= dr[rt][j];
          outb[(size_t)row * 128 + c] = (u16)f2bf(o);
        }
      }
    }
  }
}

// ---------------- pooling (bf16 input) + classifier ----------------
__global__ __launch_bounds__(128) void k_pool(
    const u16* __restrict__ hb, const int* __restrict__ batch,
    float* __restrict__ pooled, int N) {
  int f = threadIdx.x;
  int n0 = blockIdx.x * 128;
  int nEnd = min(n0 + 128, N);
  float acc = 0.f;
  int cur = -1;
  for (int nn = n0; nn < nEnd; ++nn) {
    int g = batch[nn];
    if (g != cur) {
      if (cur >= 0) atomicAdd(&pooled[cur * 128 + f], acc);
      cur = g;
      acc = 0.f;
    }
    acc += __uint_as_float((u32)hb[(size_t)nn * 128 + f] << 16);
  }
  if (cur >= 0) atomicAdd(&pooled[cur * 128 + f], acc);
}

__global__ __launch_bounds__(64) void k_cls(
    const float* __restrict__ pooled, const int* __restrict__ batch, int N,
    const float* __restrict__ Wc1, const float* __restrict__ bc1,
    const float* __restrict__ Wc2, const float* __restrict__ bc2,
    float* __restrict__ out, int G) {
  __shared__ float pm[128];
  __shared__ float hid[64];
  __shared__ float invc_s;
  int g = blockIdx.x, t = threadIdx.x;
  if (t == 0) {
    int lo = 0, hi = N;
    while (lo < hi) { int m = (lo + hi) >> 1; if (batch[m] < g) lo = m + 1; else hi = m; }
    int lb = lo;
    lo = 0; hi = N;
    while (lo < hi) { int m = (lo + hi) >> 1; if (batch[m] <= g) lo = m + 1; else hi = m; }
    invc_s = 1.f / fmaxf((float)(lo - lb), 1.f);
  }
  __syncthreads();
  float invc = invc_s;
  pm[t]      = pooled[g * 128 + t] * invc;
  pm[t + 64] = pooled[g * 128 + 64 + t] * invc;
  __syncthreads();
  float a = bc1[t];
#pragma unroll 8
  for (int k = 0; k < 128; ++k) a = fmaf(pm[k], Wc1[k * 64 + t], a);
  hid[t] = fmaxf(a, 0.f);
  __syncthreads();
  if (t < 10) {
    float a2 = bc2[t];
#pragma unroll
    for (int j = 0; j < 64; ++j) a2 = fmaf(hid[j], Wc2[j * 10 + t], a2);
    out[g * 10 + t] = a2;
  }
}

extern "C" void kernel_launch(void* const* d_in, const int* in_sizes, int n_in,
                              void* d_out, int out_size, void* d_ws, size_t ws_size,
                              hipStream_t stream) {
  const float* x   = (const float*)d_in[0];
  const int*   ei  = (const int*)d_in[1];
  const int* batch = (const int*)d_in[2];
  const float* W1 = (const float*)d_in[3];
  const float* b1 = (const float*)d_in[4];
  const float* g1 = (const float*)d_in[5];
  const float* be1 = (const float*)d_in[6];
  const float* m1 = (const float*)d_in[7];
  const float* v1 = (const float*)d_in[8];
  const float* W2 = (const float*)d_in[9];
  const float* b2 = (const float*)d_in[10];
  const float* g2 = (const float*)d_in[11];
  const float* be2 = (const float*)d_in[12];
  const float* m2 = (const float*)d_in[13];
  const float* v2 = (const float*)d_in[14];
  const float* W3 = (const float*)d_in[15];
  const float* b3 = (const float*)d_in[16];
  const float* g3 = (const float*)d_in[17];
  const float* be3 = (const float*)d_in[18];
  const float* m3 = (const float*)d_in[19];
  const float* v3 = (const float*)d_in[20];
  const float* Wc1 = (const float*)d_in[21];
  const float* bc1 = (const float*)d_in[22];
  const float* Wc2 = (const float*)d_in[23];
  const float* bc2 = (const float*)d_in[24];

  const int N = in_sizes[0] / 13;
  const int E = in_sizes[1] / 2;
  const int G = out_size / 10;
  const int* src = ei;
  const int* dst = ei + E;

  char* ws = (char*)d_ws;
  size_t off = 0;
  auto alloc = [&](size_t bytes) {
    char* p = ws + off;
    off = (off + bytes + 255) & ~(size_t)255;
    return p;
  };
  int*   deg    = (int*)  alloc((size_t)N * 4);
  float* dis    = (float*)alloc((size_t)N * 4);
  int*   pdeg   = (int*)  alloc((size_t)N * 4);
  int*   offs   = (int*)  alloc((size_t)(N + 1) * 4);
  const int nb  = (N + 255) / 256;
  int*   bsum   = (int*)  alloc((size_t)nb * 4);
  int*   bexc   = (int*)  alloc((size_t)nb * 4);
  int*   rank   = (int*)  alloc((size_t)E * 4);
  int*   csr    = (int*)  alloc(((size_t)E + 3 * (size_t)N + 8) * 4);
  u16*   hbf    = (u16*)  alloc((size_t)(N + 1) * 128 * 2);   // hs bf16 / later h3 bf16
  u16*   Ahp    = (u16*)  alloc((size_t)N * 128 * 2);         // agg out hi
  u16*   Alp    = (u16*)  alloc((size_t)N * 128 * 2);         // agg out lo residual
  float* xs     = (float*)alloc((size_t)(N + 1) * 16 * 4);    // scaled padded x
  u16*   Wht2   = (u16*)  alloc(16384 * 2);
  u16*   Wlt2   = (u16*)  alloc(16384 * 2);
  u16*   Wht3   = (u16*)  alloc(16384 * 2);
  u16*   Wlt3   = (u16*)  alloc(16384 * 2);
  float* sc2    = (float*)alloc(128 * 4);
  float* tc2    = (float*)alloc(128 * 4);
  float* sc3    = (float*)alloc(128 * 4);
  float* tc3    = (float*)alloc(128 * 4);
  float* pooled = (float*)alloc((size_t)G * 128 * 4);
  float* ax = (float*)Ahp;   // [N,16] alias (consumed before agg128 writes Ahp)

  hipMemsetAsync(deg, 0, (size_t)N * 4, stream);
  hipMemsetAsync(pooled, 0, (size_t)G * 128 * 4, stream);

  k_prep_w<<<128, 256, 0, stream>>>(W2, W3, b2, g2, be2, m2, v2, b3, g3, be3, m3, v3,
                                    Wht2, Wlt2, Wht3, Wlt3, sc2, tc2, sc3, tc3);

  const int nE8 = (E + 7) / 8;
  k_hist_rank<<<(nE8 + 255) / 256, 256, 0, stream>>>(dst, deg, rank, E);
  k_prep_nodes<<<(N + 256) / 256, 256, 0, stream>>>(deg, x, dis, pdeg, xs, N);
  k_scan_block<<<nb, 256, 0, stream>>>(pdeg, offs, bsum, N);
  k_scan_bsum<<<1, 512, 0, stream>>>(bsum, bexc, nb);
  k_add_back_pad<<<nb, 256, 0, stream>>>(offs, bexc, bsum, deg, pdeg, csr, N, nb);
  const int nE4 = (E + 3) / 4;
  k_fill_rank<<<(nE4 + 255) / 256, 256, 0, stream>>>(src, dst, rank, offs, csr, E);

  k_agg16<<<(N + 3) / 4, 64, 0, stream>>>(xs, csr, offs, dis, ax, N);
  k_gemm1<<<1024, 256, 0, stream>>>(ax, W1, b1, g1, be1, m1, v1, dis, (u32*)hbf, N);

  const int gemmGrid = (N + 127) / 128;
  k_agg128<<<(N + 3) / 4, 256, 0, stream>>>(hbf, csr, offs, dis,
                                            (uint4*)Ahp, (uint4*)Alp, N);
  k_gemm_mfma<0><<<gemmGrid, 256, 0, stream>>>(Ahp, Alp, Wht2, Wlt2, sc2, tc2, dis,
                                               hbf, N);
  k_agg128<<<(N + 3) / 4, 256, 0, stream>>>(hbf, csr, offs, dis,
                                            (uint4*)Ahp, (uint4*)Alp, N);
  k_gemm_mfma<1><<<gemmGrid, 256, 0, stream>>>(Ahp, Alp, Wht3, Wlt3, sc3, tc3, dis,
                                               hbf, N);

  k_pool<<<(N + 127) / 128, 128, 0, stream>>>(hbf, batch, pooled, N);
  k_cls<<<G, 64, 0, stream>>>(pooled, batch, N, Wc1, bc1, Wc2, bc2, (float*)d_out, G);
}